// Round 1
// baseline (762.790 us; speedup 1.0000x reference)
//
#include <hip/hip_runtime.h>

static constexpr int FC = 128;   // IC == H == 128

// ---------------- CSR build ----------------
__global__ void count_kernel(const int* __restrict__ dst, int* __restrict__ deg, int e) {
  int i = blockIdx.x * blockDim.x + threadIdx.x;
  if (i < e) atomicAdd(&deg[dst[i]], 1);
}

__global__ __launch_bounds__(1024) void scan_kernel(const int* __restrict__ deg,
                                                    int* __restrict__ off, int n) {
  __shared__ int part[1024];
  int t = threadIdx.x;
  int chunk = (n + 1023) >> 10;
  int start = t * chunk;
  int s = 0;
  for (int i = 0; i < chunk; i++) { int idx = start + i; if (idx < n) s += deg[idx]; }
  part[t] = s;
  __syncthreads();
  for (int d = 1; d < 1024; d <<= 1) {
    int v = (t >= d) ? part[t - d] : 0;
    __syncthreads();
    part[t] += v;
    __syncthreads();
  }
  int base = (t == 0) ? 0 : part[t - 1];
  for (int i = 0; i < chunk; i++) {
    int idx = start + i;
    if (idx < n) { off[idx] = base; base += deg[idx]; }
  }
  if (t == 1023) off[n] = part[1023];
}

__global__ void fill_kernel(const int* __restrict__ src, const int* __restrict__ dst,
                            const int* __restrict__ off, int* __restrict__ cur,
                            int* __restrict__ csr, int e) {
  int i = blockIdx.x * blockDim.x + threadIdx.x;
  if (i < e) {
    int d = dst[i];
    int p = atomicAdd(&cur[d], 1);
    csr[off[d] + p] = src[i];
  }
}

// ---------------- mean aggregation: one wave per node ----------------
__global__ __launch_bounds__(256) void aggregate_kernel(const float* __restrict__ x,
                                                        const int* __restrict__ off,
                                                        const int* __restrict__ csr,
                                                        float* __restrict__ agg, int n) {
  int w = (int)((blockIdx.x * blockDim.x + threadIdx.x) >> 6);
  int lane = threadIdx.x & 63;
  if (w >= n) return;
  int s0 = off[w], s1 = off[w + 1];
  float ax = 0.f, ay = 0.f;
  for (int j = s0; j < s1; j++) {
    int s = csr[j];
    float2 v = *reinterpret_cast<const float2*>(x + (size_t)s * FC + lane * 2);
    ax += v.x; ay += v.y;
  }
  int d = s1 - s0;
  float inv = 1.0f / (float)(d > 0 ? d : 1);
  float2 o; o.x = ax * inv; o.y = ay * inv;
  *reinterpret_cast<float2*>(agg + (size_t)w * FC + lane * 2) = o;
}

// ---------------- GEMM: C[N,NCOLS] = A1@W1^T (+ A2@W2^T) + bias ----------------
// A*: [nrows,128] row-major. W*: [NCOLS,128] row-major. K = DUAL ? 256 : 128.
template <int NCOLS, bool DUAL>
__global__ __launch_bounds__(256) void gemm_kernel(const float* __restrict__ A1,
                                                   const float* __restrict__ A2,
                                                   const float* __restrict__ W1,
                                                   const float* __restrict__ W2,
                                                   const float* __restrict__ bias,
                                                   float* __restrict__ C, int nrows) {
  constexpr int BM = 64, BK = 32;
  constexpr int KTOT = DUAL ? 256 : 128;
  constexpr int CPT = NCOLS / 32;   // cols per thread
  __shared__ float As[BM][BK];      // 8 KB
  __shared__ float Bs[BK][NCOLS];   // 16 KB (NCOLS=128) / 8 KB (64)

  int t = threadIdx.x;
  int tx = t & 31, ty = t >> 5;
  int row0 = blockIdx.x * BM;

  float acc[8][CPT];
#pragma unroll
  for (int i = 0; i < 8; i++)
#pragma unroll
    for (int j = 0; j < CPT; j++) acc[i][j] = 0.f;

  for (int kt = 0; kt < KTOT; kt += BK) {
    // --- load A tile: thread loads 8 contiguous k for one row ---
    {
      int r = t >> 2;
      int k0 = (t & 3) * 8;
      int gr = row0 + r;
      const float* Asrc = A1;
      int gk = kt + k0;
      if (DUAL && gk >= 128) { Asrc = A2; gk -= 128; }
      float4 v0 = {0.f, 0.f, 0.f, 0.f}, v1 = {0.f, 0.f, 0.f, 0.f};
      if (gr < nrows) {
        v0 = *reinterpret_cast<const float4*>(Asrc + (size_t)gr * 128 + gk);
        v1 = *reinterpret_cast<const float4*>(Asrc + (size_t)gr * 128 + gk + 4);
      }
      *reinterpret_cast<float4*>(&As[r][k0]) = v0;
      *reinterpret_cast<float4*>(&As[r][k0 + 4]) = v1;
    }
    // --- load B tile: Bs[kk][col] = W[col][kt+kk] ---
    {
      constexpr int GR = 256 / NCOLS;   // 2 (128) or 4 (64)
      constexpr int PK = BK / GR;       // 16 or 8
      int col = t % NCOLS;
      int kb = (t / NCOLS) * PK;
      const float* Wsrc = W1;
      int kg = kt + kb;
      if (DUAL && kt >= 128) { Wsrc = W2; kg -= 128; }
      const float* wp = Wsrc + (size_t)col * 128 + kg;
#pragma unroll
      for (int i = 0; i < PK; i++) Bs[kb + i][col] = wp[i];
    }
    __syncthreads();

#pragma unroll 8
    for (int kk = 0; kk < BK; kk++) {
      float b[CPT], a[8];
#pragma unroll
      for (int j = 0; j < CPT; j++) b[j] = Bs[kk][tx + 32 * j];
#pragma unroll
      for (int i = 0; i < 8; i++) a[i] = As[ty * 8 + i][kk];
#pragma unroll
      for (int i = 0; i < 8; i++)
#pragma unroll
        for (int j = 0; j < CPT; j++) acc[i][j] = fmaf(a[i], b[j], acc[i][j]);
    }
    __syncthreads();
  }

#pragma unroll
  for (int i = 0; i < 8; i++) {
    int gr = row0 + ty * 8 + i;
    if (gr < nrows) {
#pragma unroll
      for (int j = 0; j < CPT; j++) {
        int col = tx + 32 * j;
        C[(size_t)gr * NCOLS + col] = acc[i][j] + bias[col];
      }
    }
  }
}

// ---------------- BatchNorm ----------------
__global__ __launch_bounds__(256) void bn_stats_kernel(const float* __restrict__ h,
                                                       float* __restrict__ stats, int n) {
  int c = threadIdx.x & 127;
  int half = threadIdx.x >> 7;
  int rpb = (n + gridDim.x - 1) / gridDim.x;
  int r0 = blockIdx.x * rpb;
  int r1 = min(r0 + rpb, n);
  float s = 0.f, s2 = 0.f;
  for (int r = r0 + half; r < r1; r += 2) {
    float v = h[(size_t)r * FC + c];
    s += v; s2 += v * v;
  }
  __shared__ float ls[256];
  ls[threadIdx.x] = s;
  __syncthreads();
  if (half == 0) atomicAdd(&stats[c], s + ls[threadIdx.x + 128]);
  __syncthreads();
  ls[threadIdx.x] = s2;
  __syncthreads();
  if (half == 0) atomicAdd(&stats[128 + c], s2 + ls[threadIdx.x + 128]);
}

__global__ void bn_final_kernel(const float* __restrict__ g, const float* __restrict__ be,
                                float* __restrict__ stats, float invn) {
  int c = threadIdx.x;
  float mean = stats[c] * invn;
  float var = stats[128 + c] * invn - mean * mean;
  var = fmaxf(var, 0.f);
  float sc = g[c] * rsqrtf(var + 1e-5f);
  stats[c] = sc;
  stats[128 + c] = be[c] - mean * sc;
}

__global__ __launch_bounds__(256) void bn_apply_kernel(float* __restrict__ h,
                                                       const float* __restrict__ stats, int n) {
  int idx = blockIdx.x * blockDim.x + threadIdx.x;
  if (idx >= n * 32) return;
  int c4 = (idx & 31) * 4;
  float4 v = *reinterpret_cast<float4*>(h + (size_t)idx * 4);
  v.x = fmaxf(fmaf(v.x, stats[c4 + 0], stats[128 + c4 + 0]), 0.f);
  v.y = fmaxf(fmaf(v.y, stats[c4 + 1], stats[128 + c4 + 1]), 0.f);
  v.z = fmaxf(fmaf(v.z, stats[c4 + 2], stats[128 + c4 + 2]), 0.f);
  v.w = fmaxf(fmaf(v.w, stats[c4 + 3], stats[128 + c4 + 3]), 0.f);
  *reinterpret_cast<float4*>(h + (size_t)idx * 4) = v;
}

// ---------------- launch ----------------
extern "C" void kernel_launch(void* const* d_in, const int* in_sizes, int n_in,
                              void* d_out, int out_size, void* d_ws, size_t ws_size,
                              hipStream_t stream) {
  const float* x   = (const float*)d_in[0];
  const int*   ei  = (const int*)d_in[1];
  const float* w1l = (const float*)d_in[2];
  const float* w1r = (const float*)d_in[3];
  const float* b1c = (const float*)d_in[4];
  const float* w2l = (const float*)d_in[5];
  const float* w2r = (const float*)d_in[6];
  const float* b2c = (const float*)d_in[7];
  const float* w3l = (const float*)d_in[8];
  const float* w3r = (const float*)d_in[9];
  const float* b3c = (const float*)d_in[10];
  const float* g1  = (const float*)d_in[11];
  const float* be1 = (const float*)d_in[12];
  const float* g2  = (const float*)d_in[13];
  const float* be2 = (const float*)d_in[14];
  const float* g3  = (const float*)d_in[15];
  const float* be3 = (const float*)d_in[16];
  const float* wh  = (const float*)d_in[17];
  const float* bh  = (const float*)d_in[18];

  int n = in_sizes[0] / FC;
  int e = in_sizes[1] / 2;
  const int* srcI = ei;
  const int* dstI = ei + e;

  char* p = (char*)d_ws;
  auto take = [&](size_t bytes) {
    char* q = p;
    p += (bytes + 255) & ~(size_t)255;
    return q;
  };
  int*   deg   = (int*)take((size_t)n * 4);          // reused as cursor
  int*   off   = (int*)take((size_t)(n + 1) * 4);
  int*   csr   = (int*)take((size_t)e * 4);
  float* agg   = (float*)take((size_t)n * FC * 4);
  float* hA    = (float*)take((size_t)n * FC * 4);
  float* hB    = (float*)take((size_t)n * FC * 4);
  float* stats = (float*)take(256 * 4);

  // CSR build (graph is identical for all 3 layers)
  hipMemsetAsync(deg, 0, (size_t)n * 4, stream);
  count_kernel<<<(e + 255) / 256, 256, 0, stream>>>(dstI, deg, e);
  scan_kernel<<<1, 1024, 0, stream>>>(deg, off, n);
  hipMemsetAsync(deg, 0, (size_t)n * 4, stream);
  fill_kernel<<<(e + 255) / 256, 256, 0, stream>>>(srcI, dstI, off, deg, csr, e);

  auto layer = [&](const float* in, float* out, const float* wl, const float* wr,
                   const float* bc, const float* g, const float* be) {
    aggregate_kernel<<<(n + 3) / 4, 256, 0, stream>>>(in, off, csr, agg, n);
    gemm_kernel<128, true><<<(n + 63) / 64, 256, 0, stream>>>(agg, in, wl, wr, bc, out, n);
    hipMemsetAsync(stats, 0, 256 * 4, stream);
    bn_stats_kernel<<<256, 256, 0, stream>>>(out, stats, n);
    bn_final_kernel<<<1, 128, 0, stream>>>(g, be, stats, 1.0f / (float)n);
    bn_apply_kernel<<<(n * 32 + 255) / 256, 256, 0, stream>>>(out, stats, n);
  };

  layer(x,  hA, w1l, w1r, b1c, g1, be1);
  layer(hA, hB, w2l, w2r, b2c, g2, be2);
  layer(hB, hA, w3l, w3r, b3c, g3, be3);

  gemm_kernel<64, false><<<(n + 63) / 64, 256, 0, stream>>>(hA, nullptr, wh, nullptr, bh,
                                                            (float*)d_out, n);
}

// Round 2
// 590.939 us; speedup vs baseline: 1.2908x; 1.2908x over previous
//
#include <hip/hip_runtime.h>

static constexpr int FC = 128;   // IC == H == 128

// ---------------- CSR build ----------------
__global__ void count_kernel(const int* __restrict__ dst, int* __restrict__ deg, int e) {
  int i = blockIdx.x * blockDim.x + threadIdx.x;
  if (i < e) atomicAdd(&deg[dst[i]], 1);
}

// 3-phase exclusive scan of deg[0..n) -> off[0..n], off[n]=total
__global__ __launch_bounds__(256) void scan1_kernel(const int* __restrict__ deg,
                                                    int* __restrict__ bsum, int n) {
  int i = blockIdx.x * 256 + threadIdx.x;
  int v = (i < n) ? deg[i] : 0;
  __shared__ int ls[256];
  ls[threadIdx.x] = v;
  __syncthreads();
  for (int d = 128; d > 0; d >>= 1) {
    if (threadIdx.x < (unsigned)d) ls[threadIdx.x] += ls[threadIdx.x + d];
    __syncthreads();
  }
  if (threadIdx.x == 0) bsum[blockIdx.x] = ls[0];
}

__global__ __launch_bounds__(256) void scan2_kernel(int* __restrict__ bsum,
                                                    int* __restrict__ off, int n, int nb) {
  __shared__ int ls[256];
  int t = threadIdx.x;
  int v = (t < nb) ? bsum[t] : 0;
  ls[t] = v;
  __syncthreads();
  for (int d = 1; d < 256; d <<= 1) {
    int u = (t >= d) ? ls[t - d] : 0;
    __syncthreads();
    ls[t] += u;
    __syncthreads();
  }
  if (t < nb) bsum[t] = ls[t] - v;   // exclusive block offsets
  if (t == 255) off[n] = ls[255];    // total
}

__global__ __launch_bounds__(256) void scan3_kernel(const int* __restrict__ deg,
                                                    const int* __restrict__ bsum,
                                                    int* __restrict__ off, int n) {
  int i = blockIdx.x * 256 + threadIdx.x;
  int t = threadIdx.x;
  int v = (i < n) ? deg[i] : 0;
  __shared__ int ls[256];
  ls[t] = v;
  __syncthreads();
  for (int d = 1; d < 256; d <<= 1) {
    int u = (t >= d) ? ls[t - d] : 0;
    __syncthreads();
    ls[t] += u;
    __syncthreads();
  }
  if (i < n) off[i] = bsum[blockIdx.x] + ls[t] - v;
}

__global__ void fill_kernel(const int* __restrict__ src, const int* __restrict__ dst,
                            const int* __restrict__ off, int* __restrict__ cur,
                            int* __restrict__ csr, int e) {
  int i = blockIdx.x * blockDim.x + threadIdx.x;
  if (i < e) {
    int d = dst[i];
    int p = atomicAdd(&cur[d], 1);
    csr[off[d] + p] = src[i];
  }
}

// ---------------- mean aggregation: one half-wave per node, unroll-4 ----------------
__global__ __launch_bounds__(256) void aggregate_kernel(const float* __restrict__ x,
                                                        const int* __restrict__ off,
                                                        const int* __restrict__ csr,
                                                        float* __restrict__ agg, int n) {
  int hw = (int)((blockIdx.x * blockDim.x + threadIdx.x) >> 5);
  int lane = threadIdx.x & 31;
  if (hw >= n) return;
  int s0 = off[hw], s1 = off[hw + 1];
  float ax = 0.f, ay = 0.f, az = 0.f, aw = 0.f;
  int j = s0;
  for (; j + 4 <= s1; j += 4) {
    int i0 = csr[j], i1 = csr[j + 1], i2 = csr[j + 2], i3 = csr[j + 3];
    float4 v0 = *reinterpret_cast<const float4*>(x + (size_t)i0 * FC + lane * 4);
    float4 v1 = *reinterpret_cast<const float4*>(x + (size_t)i1 * FC + lane * 4);
    float4 v2 = *reinterpret_cast<const float4*>(x + (size_t)i2 * FC + lane * 4);
    float4 v3 = *reinterpret_cast<const float4*>(x + (size_t)i3 * FC + lane * 4);
    ax += (v0.x + v1.x) + (v2.x + v3.x);
    ay += (v0.y + v1.y) + (v2.y + v3.y);
    az += (v0.z + v1.z) + (v2.z + v3.z);
    aw += (v0.w + v1.w) + (v2.w + v3.w);
  }
  for (; j < s1; j++) {
    int i0 = csr[j];
    float4 v0 = *reinterpret_cast<const float4*>(x + (size_t)i0 * FC + lane * 4);
    ax += v0.x; ay += v0.y; az += v0.z; aw += v0.w;
  }
  int d = s1 - s0;
  float inv = 1.0f / (float)(d > 0 ? d : 1);
  float4 o;
  o.x = ax * inv; o.y = ay * inv; o.z = az * inv; o.w = aw * inv;
  *reinterpret_cast<float4*>(agg + (size_t)hw * FC + lane * 4) = o;
}

// ---------------- GEMM: C[N,NCOLS] = A1@W1^T (+ A2@W2^T) + bias ----------------
template <int NCOLS, bool DUAL>
__global__ __launch_bounds__(256) void gemm_kernel(const float* __restrict__ A1,
                                                   const float* __restrict__ A2,
                                                   const float* __restrict__ W1,
                                                   const float* __restrict__ W2,
                                                   const float* __restrict__ bias,
                                                   float* __restrict__ C, int nrows) {
  constexpr int BM = 64, BK = 32;
  constexpr int KTOT = DUAL ? 256 : 128;
  constexpr int CPT = NCOLS / 32;   // cols per thread
  __shared__ float As[BM][BK];
  __shared__ float Bs[BK][NCOLS];

  int t = threadIdx.x;
  int tx = t & 31, ty = t >> 5;
  int row0 = blockIdx.x * BM;

  float acc[8][CPT];
#pragma unroll
  for (int i = 0; i < 8; i++)
#pragma unroll
    for (int j = 0; j < CPT; j++) acc[i][j] = 0.f;

  for (int kt = 0; kt < KTOT; kt += BK) {
    {
      int r = t >> 2;
      int k0 = (t & 3) * 8;
      int gr = row0 + r;
      const float* Asrc = A1;
      int gk = kt + k0;
      if (DUAL && gk >= 128) { Asrc = A2; gk -= 128; }
      float4 v0 = {0.f, 0.f, 0.f, 0.f}, v1 = {0.f, 0.f, 0.f, 0.f};
      if (gr < nrows) {
        v0 = *reinterpret_cast<const float4*>(Asrc + (size_t)gr * 128 + gk);
        v1 = *reinterpret_cast<const float4*>(Asrc + (size_t)gr * 128 + gk + 4);
      }
      *reinterpret_cast<float4*>(&As[r][k0]) = v0;
      *reinterpret_cast<float4*>(&As[r][k0 + 4]) = v1;
    }
    {
      constexpr int GR = 256 / NCOLS;
      constexpr int PK = BK / GR;
      int col = t % NCOLS;
      int kb = (t / NCOLS) * PK;
      const float* Wsrc = W1;
      int kg = kt + kb;
      if (DUAL && kt >= 128) { Wsrc = W2; kg -= 128; }
      const float* wp = Wsrc + (size_t)col * 128 + kg;
#pragma unroll
      for (int i = 0; i < PK; i++) Bs[kb + i][col] = wp[i];
    }
    __syncthreads();

#pragma unroll 8
    for (int kk = 0; kk < BK; kk++) {
      float b[CPT], a[8];
#pragma unroll
      for (int j = 0; j < CPT; j++) b[j] = Bs[kk][tx + 32 * j];
#pragma unroll
      for (int i = 0; i < 8; i++) a[i] = As[ty * 8 + i][kk];
#pragma unroll
      for (int i = 0; i < 8; i++)
#pragma unroll
        for (int j = 0; j < CPT; j++) acc[i][j] = fmaf(a[i], b[j], acc[i][j]);
    }
    __syncthreads();
  }

#pragma unroll
  for (int i = 0; i < 8; i++) {
    int gr = row0 + ty * 8 + i;
    if (gr < nrows) {
#pragma unroll
      for (int j = 0; j < CPT; j++) {
        int col = tx + 32 * j;
        C[(size_t)gr * NCOLS + col] = acc[i][j] + bias[col];
      }
    }
  }
}

// ---------------- BatchNorm ----------------
__global__ __launch_bounds__(256) void bn_stats_kernel(const float* __restrict__ h,
                                                       float* __restrict__ stats, int n) {
  int c = threadIdx.x & 127;
  int half = threadIdx.x >> 7;
  int rpb = (n + gridDim.x - 1) / gridDim.x;
  int r0 = blockIdx.x * rpb;
  int r1 = min(r0 + rpb, n);
  float s = 0.f, s2 = 0.f;
  for (int r = r0 + half; r < r1; r += 2) {
    float v = h[(size_t)r * FC + c];
    s += v; s2 += v * v;
  }
  __shared__ float ls[256];
  ls[threadIdx.x] = s;
  __syncthreads();
  if (half == 0) atomicAdd(&stats[c], s + ls[threadIdx.x + 128]);
  __syncthreads();
  ls[threadIdx.x] = s2;
  __syncthreads();
  if (half == 0) atomicAdd(&stats[128 + c], s2 + ls[threadIdx.x + 128]);
}

__global__ void bn_final_kernel(const float* __restrict__ g, const float* __restrict__ be,
                                float* __restrict__ stats, float invn) {
  int c = threadIdx.x;
  float mean = stats[c] * invn;
  float var = stats[128 + c] * invn - mean * mean;
  var = fmaxf(var, 0.f);
  float sc = g[c] * rsqrtf(var + 1e-5f);
  stats[c] = sc;
  stats[128 + c] = be[c] - mean * sc;
}

__global__ __launch_bounds__(256) void bn_apply_kernel(float* __restrict__ h,
                                                       const float* __restrict__ stats, int n) {
  int idx = blockIdx.x * blockDim.x + threadIdx.x;
  if (idx >= n * 32) return;
  int c4 = (idx & 31) * 4;
  float4 v = *reinterpret_cast<float4*>(h + (size_t)idx * 4);
  v.x = fmaxf(fmaf(v.x, stats[c4 + 0], stats[128 + c4 + 0]), 0.f);
  v.y = fmaxf(fmaf(v.y, stats[c4 + 1], stats[128 + c4 + 1]), 0.f);
  v.z = fmaxf(fmaf(v.z, stats[c4 + 2], stats[128 + c4 + 2]), 0.f);
  v.w = fmaxf(fmaf(v.w, stats[c4 + 3], stats[128 + c4 + 3]), 0.f);
  *reinterpret_cast<float4*>(h + (size_t)idx * 4) = v;
}

// ---------------- launch ----------------
extern "C" void kernel_launch(void* const* d_in, const int* in_sizes, int n_in,
                              void* d_out, int out_size, void* d_ws, size_t ws_size,
                              hipStream_t stream) {
  const float* x   = (const float*)d_in[0];
  const int*   ei  = (const int*)d_in[1];
  const float* w1l = (const float*)d_in[2];
  const float* w1r = (const float*)d_in[3];
  const float* b1c = (const float*)d_in[4];
  const float* w2l = (const float*)d_in[5];
  const float* w2r = (const float*)d_in[6];
  const float* b2c = (const float*)d_in[7];
  const float* w3l = (const float*)d_in[8];
  const float* w3r = (const float*)d_in[9];
  const float* b3c = (const float*)d_in[10];
  const float* g1  = (const float*)d_in[11];
  const float* be1 = (const float*)d_in[12];
  const float* g2  = (const float*)d_in[13];
  const float* be2 = (const float*)d_in[14];
  const float* g3  = (const float*)d_in[15];
  const float* be3 = (const float*)d_in[16];
  const float* wh  = (const float*)d_in[17];
  const float* bh  = (const float*)d_in[18];

  int n = in_sizes[0] / FC;
  int e = in_sizes[1] / 2;
  const int* srcI = ei;
  const int* dstI = ei + e;

  char* p = (char*)d_ws;
  auto take = [&](size_t bytes) {
    char* q = p;
    p += (bytes + 255) & ~(size_t)255;
    return q;
  };
  int nb = (n + 255) / 256;
  int*   deg   = (int*)take((size_t)n * 4);          // reused as cursor
  int*   off   = (int*)take((size_t)(n + 1) * 4);
  int*   bsum  = (int*)take((size_t)nb * 4);
  int*   csr   = (int*)take((size_t)e * 4);
  float* agg   = (float*)take((size_t)n * FC * 4);
  float* hA    = (float*)take((size_t)n * FC * 4);
  float* hB    = (float*)take((size_t)n * FC * 4);
  float* stats = (float*)take(256 * 4);

  // CSR build (graph identical for all 3 layers)
  hipMemsetAsync(deg, 0, (size_t)n * 4, stream);
  count_kernel<<<(e + 255) / 256, 256, 0, stream>>>(dstI, deg, e);
  scan1_kernel<<<nb, 256, 0, stream>>>(deg, bsum, n);
  scan2_kernel<<<1, 256, 0, stream>>>(bsum, off, n, nb);
  scan3_kernel<<<nb, 256, 0, stream>>>(deg, bsum, off, n);
  hipMemsetAsync(deg, 0, (size_t)n * 4, stream);
  fill_kernel<<<(e + 255) / 256, 256, 0, stream>>>(srcI, dstI, off, deg, csr, e);

  auto layer = [&](const float* in, float* out, const float* wl, const float* wr,
                   const float* bc, const float* g, const float* be) {
    aggregate_kernel<<<(n + 7) / 8, 256, 0, stream>>>(in, off, csr, agg, n);
    gemm_kernel<128, true><<<(n + 63) / 64, 256, 0, stream>>>(agg, in, wl, wr, bc, out, n);
    hipMemsetAsync(stats, 0, 256 * 4, stream);
    bn_stats_kernel<<<256, 256, 0, stream>>>(out, stats, n);
    bn_final_kernel<<<1, 128, 0, stream>>>(g, be, stats, 1.0f / (float)n);
    bn_apply_kernel<<<(n * 32 + 255) / 256, 256, 0, stream>>>(out, stats, n);
  };

  layer(x,  hA, w1l, w1r, b1c, g1, be1);
  layer(hA, hB, w2l, w2r, b2c, g2, be2);
  layer(hB, hA, w3l, w3r, b3c, g3, be3);

  gemm_kernel<64, false><<<(n + 63) / 64, 256, 0, stream>>>(hA, nullptr, wh, nullptr, bh,
                                                            (float*)d_out, n);
}

// Round 3
// 445.731 us; speedup vs baseline: 1.7113x; 1.3258x over previous
//
#include <hip/hip_runtime.h>

static constexpr int FC = 128;

typedef __attribute__((ext_vector_type(8))) __bf16 bf16x8;
typedef __attribute__((ext_vector_type(4))) float f32x4;

__device__ __forceinline__ unsigned short f2bf(float f) {
  unsigned u = __float_as_uint(f);
  unsigned r = (u + 0x7FFF + ((u >> 16) & 1)) >> 16;
  return (unsigned short)r;
}
__device__ __forceinline__ float bf2f(unsigned short h) {
  return __uint_as_float((unsigned)h << 16);
}

// ---------------- fp32 -> bf16 conversion (8 elems/thread) ----------------
__global__ __launch_bounds__(256) void f2bf_kernel(const float* __restrict__ in,
                                                   unsigned short* __restrict__ out, int n8) {
  int i = blockIdx.x * 256 + threadIdx.x;
  if (i >= n8) return;
  const float* p = in + (size_t)i * 8;
  float4 a = *reinterpret_cast<const float4*>(p);
  float4 b = *reinterpret_cast<const float4*>(p + 4);
  ushort4 o0 = {f2bf(a.x), f2bf(a.y), f2bf(a.z), f2bf(a.w)};
  ushort4 o1 = {f2bf(b.x), f2bf(b.y), f2bf(b.z), f2bf(b.w)};
  unsigned short* q = out + (size_t)i * 8;
  *reinterpret_cast<ushort4*>(q) = o0;
  *reinterpret_cast<ushort4*>(q + 4) = o1;
}

// pack wl[128][128] | wr[128][128] -> wcat[128][256] bf16
__global__ __launch_bounds__(256) void pack_w_kernel(const float* __restrict__ wl,
                                                     const float* __restrict__ wr,
                                                     unsigned short* __restrict__ out) {
  int i = blockIdx.x * 256 + threadIdx.x;   // 0..4095, 8 elems each
  int row = i >> 5;
  int k8 = (i & 31) * 8;
  const float* src = (k8 < 128) ? (wl + (size_t)row * 128 + k8)
                                : (wr + (size_t)row * 128 + (k8 - 128));
  float4 a = *reinterpret_cast<const float4*>(src);
  float4 b = *reinterpret_cast<const float4*>(src + 4);
  ushort4 o0 = {f2bf(a.x), f2bf(a.y), f2bf(a.z), f2bf(a.w)};
  ushort4 o1 = {f2bf(b.x), f2bf(b.y), f2bf(b.z), f2bf(b.w)};
  unsigned short* q = out + (size_t)row * 256 + k8;
  *reinterpret_cast<ushort4*>(q) = o0;
  *reinterpret_cast<ushort4*>(q + 4) = o1;
}

// ---------------- CSR build ----------------
__global__ void count_kernel(const int* __restrict__ dst, int* __restrict__ deg, int e) {
  int i = blockIdx.x * blockDim.x + threadIdx.x;
  if (i < e) atomicAdd(&deg[dst[i]], 1);
}

__global__ __launch_bounds__(256) void scan1_kernel(const int* __restrict__ deg,
                                                    int* __restrict__ bsum, int n) {
  int i = blockIdx.x * 256 + threadIdx.x;
  int v = (i < n) ? deg[i] : 0;
  __shared__ int ls[256];
  ls[threadIdx.x] = v;
  __syncthreads();
  for (int d = 128; d > 0; d >>= 1) {
    if (threadIdx.x < (unsigned)d) ls[threadIdx.x] += ls[threadIdx.x + d];
    __syncthreads();
  }
  if (threadIdx.x == 0) bsum[blockIdx.x] = ls[0];
}

__global__ __launch_bounds__(256) void scan2_kernel(int* __restrict__ bsum,
                                                    int* __restrict__ off, int n, int nb) {
  __shared__ int ls[256];
  int t = threadIdx.x;
  int v = (t < nb) ? bsum[t] : 0;
  ls[t] = v;
  __syncthreads();
  for (int d = 1; d < 256; d <<= 1) {
    int u = (t >= d) ? ls[t - d] : 0;
    __syncthreads();
    ls[t] += u;
    __syncthreads();
  }
  if (t < nb) bsum[t] = ls[t] - v;
  if (t == 255) off[n] = ls[255];
}

__global__ __launch_bounds__(256) void scan3_kernel(const int* __restrict__ deg,
                                                    const int* __restrict__ bsum,
                                                    int* __restrict__ off, int n) {
  int i = blockIdx.x * 256 + threadIdx.x;
  int t = threadIdx.x;
  int v = (i < n) ? deg[i] : 0;
  __shared__ int ls[256];
  ls[t] = v;
  __syncthreads();
  for (int d = 1; d < 256; d <<= 1) {
    int u = (t >= d) ? ls[t - d] : 0;
    __syncthreads();
    ls[t] += u;
    __syncthreads();
  }
  if (i < n) off[i] = bsum[blockIdx.x] + ls[t] - v;
}

__global__ void fill_kernel(const int* __restrict__ src, const int* __restrict__ dst,
                            const int* __restrict__ off, int* __restrict__ cur,
                            int* __restrict__ csr, int e) {
  int i = blockIdx.x * blockDim.x + threadIdx.x;
  if (i < e) {
    int d = dst[i];
    int p = atomicAdd(&cur[d], 1);
    csr[off[d] + p] = src[i];
  }
}

// ---------------- mean aggregation (bf16 in/out): half-wave per node ----------------
__global__ __launch_bounds__(256) void aggregate_kernel(const unsigned short* __restrict__ x,
                                                        const int* __restrict__ off,
                                                        const int* __restrict__ csr,
                                                        unsigned short* __restrict__ agg, int n) {
  int hw = (int)((blockIdx.x * blockDim.x + threadIdx.x) >> 5);
  int lane = threadIdx.x & 31;
  if (hw >= n) return;
  int s0 = off[hw], s1 = off[hw + 1];
  float a0 = 0.f, a1 = 0.f, a2 = 0.f, a3 = 0.f;
  int j = s0;
  for (; j + 4 <= s1; j += 4) {
    int i0 = csr[j], i1 = csr[j + 1], i2 = csr[j + 2], i3 = csr[j + 3];
    ushort4 v0 = *reinterpret_cast<const ushort4*>(x + (size_t)i0 * FC + lane * 4);
    ushort4 v1 = *reinterpret_cast<const ushort4*>(x + (size_t)i1 * FC + lane * 4);
    ushort4 v2 = *reinterpret_cast<const ushort4*>(x + (size_t)i2 * FC + lane * 4);
    ushort4 v3 = *reinterpret_cast<const ushort4*>(x + (size_t)i3 * FC + lane * 4);
    a0 += (bf2f(v0.x) + bf2f(v1.x)) + (bf2f(v2.x) + bf2f(v3.x));
    a1 += (bf2f(v0.y) + bf2f(v1.y)) + (bf2f(v2.y) + bf2f(v3.y));
    a2 += (bf2f(v0.z) + bf2f(v1.z)) + (bf2f(v2.z) + bf2f(v3.z));
    a3 += (bf2f(v0.w) + bf2f(v1.w)) + (bf2f(v2.w) + bf2f(v3.w));
  }
  for (; j < s1; j++) {
    int i0 = csr[j];
    ushort4 v0 = *reinterpret_cast<const ushort4*>(x + (size_t)i0 * FC + lane * 4);
    a0 += bf2f(v0.x); a1 += bf2f(v0.y); a2 += bf2f(v0.z); a3 += bf2f(v0.w);
  }
  int d = s1 - s0;
  float inv = 1.0f / (float)(d > 0 ? d : 1);
  ushort4 o = {f2bf(a0 * inv), f2bf(a1 * inv), f2bf(a2 * inv), f2bf(a3 * inv)};
  *reinterpret_cast<ushort4*>(agg + (size_t)hw * FC + lane * 4) = o;
}

// ---------------- MFMA GEMM: C[nrows,NCOLS] = [A1|A2] @ Wcat^T + bias ----------------
// A1/A2: [nrows][128] bf16. Wcat: [NCOLS][KTOT] bf16 row-major (contiguous K).
// Per wave: 16 rows x NCOLS cols; block = 4 waves = 64 rows.
template <int NCOLS, int KTOT, bool DUAL, bool OUT_BF>
__global__ __launch_bounds__(256) void gemm_kernel(const unsigned short* __restrict__ A1,
                                                   const unsigned short* __restrict__ A2,
                                                   const unsigned short* __restrict__ W,
                                                   const float* __restrict__ bias,
                                                   void* __restrict__ Cout, int nrows) {
  constexpr int NKT = KTOT / 32;
  constexpr int NCF = NCOLS / 16;
  int w = threadIdx.x >> 6;
  int l = threadIdx.x & 63;
  int lm = l & 15;
  int lk = (l >> 4) * 8;
  int row = blockIdx.x * 64 + w * 16 + lm;
  int rclamp = min(row, nrows - 1);

  f32x4 acc[NCF];
#pragma unroll
  for (int cf = 0; cf < NCF; cf++) acc[cf] = {0.f, 0.f, 0.f, 0.f};

#pragma unroll
  for (int kt = 0; kt < NKT; kt++) {
    const unsigned short* Ap;
    int kk;
    if (!DUAL || kt < NKT / 2) { Ap = A1; kk = kt * 32; }
    else                       { Ap = A2; kk = (kt - NKT / 2) * 32; }
    bf16x8 a = *reinterpret_cast<const bf16x8*>(Ap + (size_t)rclamp * 128 + kk + lk);
#pragma unroll
    for (int cf = 0; cf < NCF; cf++) {
      bf16x8 b = *reinterpret_cast<const bf16x8*>(W + (size_t)(cf * 16 + lm) * KTOT + kt * 32 + lk);
      acc[cf] = __builtin_amdgcn_mfma_f32_16x16x32_bf16(a, b, acc[cf], 0, 0, 0);
    }
  }

  int orow0 = blockIdx.x * 64 + w * 16 + (l >> 4) * 4;
#pragma unroll
  for (int cf = 0; cf < NCF; cf++) {
    int col = cf * 16 + lm;
    float bs = bias[col];
#pragma unroll
    for (int r = 0; r < 4; r++) {
      int orow = orow0 + r;
      if (orow < nrows) {
        float v = acc[cf][r] + bs;
        if (OUT_BF)
          ((unsigned short*)Cout)[(size_t)orow * NCOLS + col] = f2bf(v);
        else
          ((float*)Cout)[(size_t)orow * NCOLS + col] = v;
      }
    }
  }
}

// ---------------- BatchNorm (bf16 activations, fp32 stats) ----------------
__global__ __launch_bounds__(256) void bn_stats_kernel(const unsigned short* __restrict__ h,
                                                       float* __restrict__ stats, int n) {
  int c = threadIdx.x & 127;
  int half = threadIdx.x >> 7;
  int rpb = (n + gridDim.x - 1) / gridDim.x;
  int r0 = blockIdx.x * rpb;
  int r1 = min(r0 + rpb, n);
  float s = 0.f, s2 = 0.f;
  for (int r = r0 + half; r < r1; r += 2) {
    float v = bf2f(h[(size_t)r * FC + c]);
    s += v; s2 += v * v;
  }
  __shared__ float ls[256];
  ls[threadIdx.x] = s;
  __syncthreads();
  if (half == 0) atomicAdd(&stats[c], s + ls[threadIdx.x + 128]);
  __syncthreads();
  ls[threadIdx.x] = s2;
  __syncthreads();
  if (half == 0) atomicAdd(&stats[128 + c], s2 + ls[threadIdx.x + 128]);
}

__global__ void bn_final_kernel(const float* __restrict__ g, const float* __restrict__ be,
                                float* __restrict__ stats, float invn) {
  int c = threadIdx.x;
  float mean = stats[c] * invn;
  float var = stats[128 + c] * invn - mean * mean;
  var = fmaxf(var, 0.f);
  float sc = g[c] * rsqrtf(var + 1e-5f);
  stats[c] = sc;
  stats[128 + c] = be[c] - mean * sc;
}

__global__ __launch_bounds__(256) void bn_apply_kernel(unsigned short* __restrict__ h,
                                                       const float* __restrict__ stats, int n) {
  int idx = blockIdx.x * blockDim.x + threadIdx.x;
  if (idx >= n * 16) return;
  int c8 = (idx & 15) * 8;
  unsigned short* p = h + (size_t)idx * 8;
  ushort4 v0 = *reinterpret_cast<const ushort4*>(p);
  ushort4 v1 = *reinterpret_cast<const ushort4*>(p + 4);
  float o[8];
  o[0] = bf2f(v0.x); o[1] = bf2f(v0.y); o[2] = bf2f(v0.z); o[3] = bf2f(v0.w);
  o[4] = bf2f(v1.x); o[5] = bf2f(v1.y); o[6] = bf2f(v1.z); o[7] = bf2f(v1.w);
#pragma unroll
  for (int i = 0; i < 8; i++)
    o[i] = fmaxf(fmaf(o[i], stats[c8 + i], stats[128 + c8 + i]), 0.f);
  ushort4 w0 = {f2bf(o[0]), f2bf(o[1]), f2bf(o[2]), f2bf(o[3])};
  ushort4 w1 = {f2bf(o[4]), f2bf(o[5]), f2bf(o[6]), f2bf(o[7])};
  *reinterpret_cast<ushort4*>(p) = w0;
  *reinterpret_cast<ushort4*>(p + 4) = w1;
}

// ---------------- launch ----------------
extern "C" void kernel_launch(void* const* d_in, const int* in_sizes, int n_in,
                              void* d_out, int out_size, void* d_ws, size_t ws_size,
                              hipStream_t stream) {
  const float* x   = (const float*)d_in[0];
  const int*   ei  = (const int*)d_in[1];
  const float* w1l = (const float*)d_in[2];
  const float* w1r = (const float*)d_in[3];
  const float* b1c = (const float*)d_in[4];
  const float* w2l = (const float*)d_in[5];
  const float* w2r = (const float*)d_in[6];
  const float* b2c = (const float*)d_in[7];
  const float* w3l = (const float*)d_in[8];
  const float* w3r = (const float*)d_in[9];
  const float* b3c = (const float*)d_in[10];
  const float* g1  = (const float*)d_in[11];
  const float* be1 = (const float*)d_in[12];
  const float* g2  = (const float*)d_in[13];
  const float* be2 = (const float*)d_in[14];
  const float* g3  = (const float*)d_in[15];
  const float* be3 = (const float*)d_in[16];
  const float* wh  = (const float*)d_in[17];
  const float* bh  = (const float*)d_in[18];

  int n = in_sizes[0] / FC;
  int e = in_sizes[1] / 2;
  const int* srcI = ei;
  const int* dstI = ei + e;

  char* p = (char*)d_ws;
  auto take = [&](size_t bytes) {
    char* q = p;
    p += (bytes + 255) & ~(size_t)255;
    return q;
  };
  int nb = (n + 255) / 256;
  int* deg  = (int*)take((size_t)n * 4);
  int* off  = (int*)take((size_t)(n + 1) * 4);
  int* bsum = (int*)take((size_t)nb * 4);
  int* csr  = (int*)take((size_t)e * 4);
  unsigned short* x_bf = (unsigned short*)take((size_t)n * FC * 2);
  unsigned short* agg  = (unsigned short*)take((size_t)n * FC * 2);
  unsigned short* h1   = (unsigned short*)take((size_t)n * FC * 2);
  unsigned short* h2   = (unsigned short*)take((size_t)n * FC * 2);
  unsigned short* wc1  = (unsigned short*)take(128 * 256 * 2);
  unsigned short* wc2  = (unsigned short*)take(128 * 256 * 2);
  unsigned short* wc3  = (unsigned short*)take(128 * 256 * 2);
  unsigned short* whb  = (unsigned short*)take(64 * 128 * 2);
  float* stats = (float*)take(256 * 4);

  // one-time conversions
  f2bf_kernel<<<(n * 16 + 255) / 256, 256, 0, stream>>>(x, x_bf, n * 16);
  pack_w_kernel<<<16, 256, 0, stream>>>(w1l, w1r, wc1);
  pack_w_kernel<<<16, 256, 0, stream>>>(w2l, w2r, wc2);
  pack_w_kernel<<<16, 256, 0, stream>>>(w3l, w3r, wc3);
  f2bf_kernel<<<4, 256, 0, stream>>>(wh, whb, 64 * 128 / 8);

  // CSR build
  hipMemsetAsync(deg, 0, (size_t)n * 4, stream);
  count_kernel<<<(e + 255) / 256, 256, 0, stream>>>(dstI, deg, e);
  scan1_kernel<<<nb, 256, 0, stream>>>(deg, bsum, n);
  scan2_kernel<<<1, 256, 0, stream>>>(bsum, off, n, nb);
  scan3_kernel<<<nb, 256, 0, stream>>>(deg, bsum, off, n);
  hipMemsetAsync(deg, 0, (size_t)n * 4, stream);
  fill_kernel<<<(e + 255) / 256, 256, 0, stream>>>(srcI, dstI, off, deg, csr, e);

  auto layer = [&](const unsigned short* in, unsigned short* out, const unsigned short* wc,
                   const float* bc, const float* g, const float* be) {
    aggregate_kernel<<<(n + 7) / 8, 256, 0, stream>>>(in, off, csr, agg, n);
    gemm_kernel<128, 256, true, true><<<(n + 63) / 64, 256, 0, stream>>>(agg, in, wc, bc, out, n);
    hipMemsetAsync(stats, 0, 256 * 4, stream);
    bn_stats_kernel<<<256, 256, 0, stream>>>(out, stats, n);
    bn_final_kernel<<<1, 128, 0, stream>>>(g, be, stats, 1.0f / (float)n);
    bn_apply_kernel<<<(n * 16 + 255) / 256, 256, 0, stream>>>(out, stats, n);
  };

  layer(x_bf, h1, wc1, b1c, g1, be1);
  layer(h1,   h2, wc2, b2c, g2, be2);
  layer(h2,   h1, wc3, b3c, g3, be3);

  gemm_kernel<64, 128, false, false><<<(n + 63) / 64, 256, 0, stream>>>(
      h1, nullptr, whb, bh, d_out, n);
}

// Round 5
// 350.551 us; speedup vs baseline: 2.1760x; 1.2715x over previous
//
#include <hip/hip_runtime.h>

static constexpr int FC = 128;

typedef __attribute__((ext_vector_type(8))) __bf16 bf16x8;
typedef __attribute__((ext_vector_type(4))) float f32x4;

__device__ __forceinline__ unsigned short f2bf(float f) {
  unsigned u = __float_as_uint(f);
  unsigned r = (u + 0x7FFF + ((u >> 16) & 1)) >> 16;
  return (unsigned short)r;
}
__device__ __forceinline__ float bf2f(unsigned short h) {
  return __uint_as_float((unsigned)h << 16);
}

// ---------------- fp32 -> bf16 conversion (8 elems/thread) ----------------
__global__ __launch_bounds__(256) void f2bf_kernel(const float* __restrict__ in,
                                                   unsigned short* __restrict__ out, int n8) {
  int i = blockIdx.x * 256 + threadIdx.x;
  if (i >= n8) return;
  const float* p = in + (size_t)i * 8;
  float4 a = *reinterpret_cast<const float4*>(p);
  float4 b = *reinterpret_cast<const float4*>(p + 4);
  ushort4 o0 = {f2bf(a.x), f2bf(a.y), f2bf(a.z), f2bf(a.w)};
  ushort4 o1 = {f2bf(b.x), f2bf(b.y), f2bf(b.z), f2bf(b.w)};
  unsigned short* q = out + (size_t)i * 8;
  *reinterpret_cast<ushort4*>(q) = o0;
  *reinterpret_cast<ushort4*>(q + 4) = o1;
}

// pack wl[128][128] | wr[128][128] -> wcat[128][256] bf16
__global__ __launch_bounds__(256) void pack_w_kernel(const float* __restrict__ wl,
                                                     const float* __restrict__ wr,
                                                     unsigned short* __restrict__ out) {
  int i = blockIdx.x * 256 + threadIdx.x;
  int row = i >> 5;
  int k8 = (i & 31) * 8;
  const float* src = (k8 < 128) ? (wl + (size_t)row * 128 + k8)
                                : (wr + (size_t)row * 128 + (k8 - 128));
  float4 a = *reinterpret_cast<const float4*>(src);
  float4 b = *reinterpret_cast<const float4*>(src + 4);
  ushort4 o0 = {f2bf(a.x), f2bf(a.y), f2bf(a.z), f2bf(a.w)};
  ushort4 o1 = {f2bf(b.x), f2bf(b.y), f2bf(b.z), f2bf(b.w)};
  unsigned short* q = out + (size_t)row * 256 + k8;
  *reinterpret_cast<ushort4*>(q) = o0;
  *reinterpret_cast<ushort4*>(q + 4) = o1;
}

// ---------------- CSR build ----------------
// count also emits each edge's rank within its dst bucket -> fill needs no atomic
__global__ void count_kernel(const int* __restrict__ dst, int* __restrict__ deg,
                             int* __restrict__ rank, int e) {
  int i = blockIdx.x * blockDim.x + threadIdx.x;
  if (i < e) rank[i] = atomicAdd(&deg[dst[i]], 1);
}

__global__ __launch_bounds__(256) void scan1_kernel(const int* __restrict__ deg,
                                                    int* __restrict__ bsum, int n) {
  int i = blockIdx.x * 256 + threadIdx.x;
  int v = (i < n) ? deg[i] : 0;
  __shared__ int ls[256];
  ls[threadIdx.x] = v;
  __syncthreads();
  for (int d = 128; d > 0; d >>= 1) {
    if (threadIdx.x < (unsigned)d) ls[threadIdx.x] += ls[threadIdx.x + d];
    __syncthreads();
  }
  if (threadIdx.x == 0) bsum[blockIdx.x] = ls[0];
}

__global__ __launch_bounds__(256) void scan2_kernel(int* __restrict__ bsum,
                                                    int* __restrict__ off, int n, int nb) {
  __shared__ int ls[256];
  int t = threadIdx.x;
  int v = (t < nb) ? bsum[t] : 0;
  ls[t] = v;
  __syncthreads();
  for (int d = 1; d < 256; d <<= 1) {
    int u = (t >= d) ? ls[t - d] : 0;
    __syncthreads();
    ls[t] += u;
    __syncthreads();
  }
  if (t < nb) bsum[t] = ls[t] - v;
  if (t == 255) off[n] = ls[255];
}

__global__ __launch_bounds__(256) void scan3_kernel(const int* __restrict__ deg,
                                                    const int* __restrict__ bsum,
                                                    int* __restrict__ off, int n) {
  int i = blockIdx.x * 256 + threadIdx.x;
  int t = threadIdx.x;
  int v = (i < n) ? deg[i] : 0;
  __shared__ int ls[256];
  ls[t] = v;
  __syncthreads();
  for (int d = 1; d < 256; d <<= 1) {
    int u = (t >= d) ? ls[t - d] : 0;
    __syncthreads();
    ls[t] += u;
    __syncthreads();
  }
  if (i < n) off[i] = bsum[blockIdx.x] + ls[t] - v;
}

__global__ void fill_kernel(const int* __restrict__ src, const int* __restrict__ dst,
                            const int* __restrict__ rank, const int* __restrict__ off,
                            int* __restrict__ csr, int e) {
  int i = blockIdx.x * blockDim.x + threadIdx.x;
  if (i < e) csr[off[dst[i]] + rank[i]] = src[i];
}

// ---------------- mean aggregation (bf16 in/out): half-wave per node ----------------
__global__ __launch_bounds__(256) void aggregate_kernel(const unsigned short* __restrict__ x,
                                                        const int* __restrict__ off,
                                                        const int* __restrict__ csr,
                                                        unsigned short* __restrict__ agg, int n) {
  int hw = (int)((blockIdx.x * blockDim.x + threadIdx.x) >> 5);
  int lane = threadIdx.x & 31;
  if (hw >= n) return;
  int s0 = off[hw], s1 = off[hw + 1];
  float a0 = 0.f, a1 = 0.f, a2 = 0.f, a3 = 0.f;
  int j = s0;
  for (; j + 4 <= s1; j += 4) {
    int i0 = csr[j], i1 = csr[j + 1], i2 = csr[j + 2], i3 = csr[j + 3];
    ushort4 v0 = *reinterpret_cast<const ushort4*>(x + (size_t)i0 * FC + lane * 4);
    ushort4 v1 = *reinterpret_cast<const ushort4*>(x + (size_t)i1 * FC + lane * 4);
    ushort4 v2 = *reinterpret_cast<const ushort4*>(x + (size_t)i2 * FC + lane * 4);
    ushort4 v3 = *reinterpret_cast<const ushort4*>(x + (size_t)i3 * FC + lane * 4);
    a0 += (bf2f(v0.x) + bf2f(v1.x)) + (bf2f(v2.x) + bf2f(v3.x));
    a1 += (bf2f(v0.y) + bf2f(v1.y)) + (bf2f(v2.y) + bf2f(v3.y));
    a2 += (bf2f(v0.z) + bf2f(v1.z)) + (bf2f(v2.z) + bf2f(v3.z));
    a3 += (bf2f(v0.w) + bf2f(v1.w)) + (bf2f(v2.w) + bf2f(v3.w));
  }
  for (; j < s1; j++) {
    int i0 = csr[j];
    ushort4 v0 = *reinterpret_cast<const ushort4*>(x + (size_t)i0 * FC + lane * 4);
    a0 += bf2f(v0.x); a1 += bf2f(v0.y); a2 += bf2f(v0.z); a3 += bf2f(v0.w);
  }
  int d = s1 - s0;
  float inv = 1.0f / (float)(d > 0 ? d : 1);
  ushort4 o = {f2bf(a0 * inv), f2bf(a1 * inv), f2bf(a2 * inv), f2bf(a3 * inv)};
  *reinterpret_cast<ushort4*>(agg + (size_t)hw * FC + lane * 4) = o;
}

// ---------------- MFMA GEMM + optional fused BN-stat accumulation ----------------
// C[nrows,NCOLS] = [A1|A2] @ W^T + bias. W: [NCOLS][KTOT] bf16 row-major.
// STATS: atomically accumulate per-column sum / sumsq of C into stats[0..NCOLS)
//        and stats[NCOLS..2*NCOLS).
template <int NCOLS, int KTOT, bool DUAL, bool OUT_BF, bool STATS>
__global__ __launch_bounds__(256) void gemm_kernel(const unsigned short* __restrict__ A1,
                                                   const unsigned short* __restrict__ A2,
                                                   const unsigned short* __restrict__ W,
                                                   const float* __restrict__ bias,
                                                   void* __restrict__ Cout,
                                                   float* __restrict__ stats, int nrows) {
  constexpr int NKT = KTOT / 32;
  constexpr int NCF = NCOLS / 16;
  int w = threadIdx.x >> 6;
  int l = threadIdx.x & 63;
  int lm = l & 15;
  int lk = (l >> 4) * 8;
  int row = blockIdx.x * 64 + w * 16 + lm;
  int rclamp = min(row, nrows - 1);

  f32x4 acc[NCF];
#pragma unroll
  for (int cf = 0; cf < NCF; cf++) acc[cf] = {0.f, 0.f, 0.f, 0.f};

#pragma unroll
  for (int kt = 0; kt < NKT; kt++) {
    const unsigned short* Ap;
    int kk;
    if (!DUAL || kt < NKT / 2) { Ap = A1; kk = kt * 32; }
    else                       { Ap = A2; kk = (kt - NKT / 2) * 32; }
    bf16x8 a = *reinterpret_cast<const bf16x8*>(Ap + (size_t)rclamp * 128 + kk + lk);
#pragma unroll
    for (int cf = 0; cf < NCF; cf++) {
      bf16x8 b = *reinterpret_cast<const bf16x8*>(W + (size_t)(cf * 16 + lm) * KTOT + kt * 32 + lk);
      acc[cf] = __builtin_amdgcn_mfma_f32_16x16x32_bf16(a, b, acc[cf], 0, 0, 0);
    }
  }

  __shared__ float wsum[4][NCOLS];
  __shared__ float wsq[4][NCOLS];

  int orow0 = blockIdx.x * 64 + w * 16 + (l >> 4) * 4;
#pragma unroll
  for (int cf = 0; cf < NCF; cf++) {
    int col = cf * 16 + lm;
    float bs = bias[col];
    float s = 0.f, s2 = 0.f;
#pragma unroll
    for (int r = 0; r < 4; r++) {
      int orow = orow0 + r;
      bool ok = orow < nrows;
      float v = acc[cf][r] + bs;
      if (ok) {
        if (OUT_BF)
          ((unsigned short*)Cout)[(size_t)orow * NCOLS + col] = f2bf(v);
        else
          ((float*)Cout)[(size_t)orow * NCOLS + col] = v;
      }
      if (STATS) {
        float vv = ok ? v : 0.f;
        s += vv; s2 += vv * vv;
      }
    }
    if (STATS) {
      s  += __shfl_xor(s, 16);  s  += __shfl_xor(s, 32);
      s2 += __shfl_xor(s2, 16); s2 += __shfl_xor(s2, 32);
      if (l < 16) { wsum[w][col] = s; wsq[w][col] = s2; }
    }
  }
  if (STATS) {
    __syncthreads();
    int t = threadIdx.x;
    if (t < NCOLS) {
      atomicAdd(&stats[t], wsum[0][t] + wsum[1][t] + wsum[2][t] + wsum[3][t]);
    } else if (t < 2 * NCOLS) {
      int c = t - NCOLS;
      atomicAdd(&stats[t], wsq[0][c] + wsq[1][c] + wsq[2][c] + wsq[3][c]);
    }
  }
}

// ---------------- BN finalize + apply + ReLU (folded) ----------------
__global__ __launch_bounds__(256) void bn_apply_kernel(unsigned short* __restrict__ h,
                                                       const float* __restrict__ stats,
                                                       const float* __restrict__ g,
                                                       const float* __restrict__ be,
                                                       float invn, int n) {
  __shared__ float sc[128], sh[128];
  int t = threadIdx.x;
  if (t < 128) {
    float mean = stats[t] * invn;
    float var = fmaxf(stats[128 + t] * invn - mean * mean, 0.f);
    float s = g[t] * rsqrtf(var + 1e-5f);
    sc[t] = s;
    sh[t] = be[t] - mean * s;
  }
  __syncthreads();
  int idx = blockIdx.x * 256 + t;
  if (idx >= n * 16) return;
  int c8 = (idx & 15) * 8;
  unsigned short* p = h + (size_t)idx * 8;
  ushort4 v0 = *reinterpret_cast<const ushort4*>(p);
  ushort4 v1 = *reinterpret_cast<const ushort4*>(p + 4);
  float o[8];
  o[0] = bf2f(v0.x); o[1] = bf2f(v0.y); o[2] = bf2f(v0.z); o[3] = bf2f(v0.w);
  o[4] = bf2f(v1.x); o[5] = bf2f(v1.y); o[6] = bf2f(v1.z); o[7] = bf2f(v1.w);
#pragma unroll
  for (int i = 0; i < 8; i++)
    o[i] = fmaxf(fmaf(o[i], sc[c8 + i], sh[c8 + i]), 0.f);
  ushort4 w0 = {f2bf(o[0]), f2bf(o[1]), f2bf(o[2]), f2bf(o[3])};
  ushort4 w1 = {f2bf(o[4]), f2bf(o[5]), f2bf(o[6]), f2bf(o[7])};
  *reinterpret_cast<ushort4*>(p) = w0;
  *reinterpret_cast<ushort4*>(p + 4) = w1;
}

// ---------------- launch ----------------
extern "C" void kernel_launch(void* const* d_in, const int* in_sizes, int n_in,
                              void* d_out, int out_size, void* d_ws, size_t ws_size,
                              hipStream_t stream) {
  const float* x   = (const float*)d_in[0];
  const int*   ei  = (const int*)d_in[1];
  const float* w1l = (const float*)d_in[2];
  const float* w1r = (const float*)d_in[3];
  const float* b1c = (const float*)d_in[4];
  const float* w2l = (const float*)d_in[5];
  const float* w2r = (const float*)d_in[6];
  const float* b2c = (const float*)d_in[7];
  const float* w3l = (const float*)d_in[8];
  const float* w3r = (const float*)d_in[9];
  const float* b3c = (const float*)d_in[10];
  const float* g1  = (const float*)d_in[11];
  const float* be1 = (const float*)d_in[12];
  const float* g2  = (const float*)d_in[13];
  const float* be2 = (const float*)d_in[14];
  const float* g3  = (const float*)d_in[15];
  const float* be3 = (const float*)d_in[16];
  const float* wh  = (const float*)d_in[17];
  const float* bh  = (const float*)d_in[18];

  int n = in_sizes[0] / FC;
  int e = in_sizes[1] / 2;
  const int* srcI = ei;
  const int* dstI = ei + e;

  char* p = (char*)d_ws;
  auto take = [&](size_t bytes) {
    char* q = p;
    p += (bytes + 255) & ~(size_t)255;
    return q;
  };
  int nb = (n + 255) / 256;
  int* deg  = (int*)take((size_t)n * 4);
  int* off  = (int*)take((size_t)(n + 1) * 4);
  int* bsum = (int*)take((size_t)nb * 4);
  int* rank = (int*)take((size_t)e * 4);
  int* csr  = (int*)take((size_t)e * 4);
  unsigned short* x_bf = (unsigned short*)take((size_t)n * FC * 2);
  unsigned short* agg  = (unsigned short*)take((size_t)n * FC * 2);
  unsigned short* h1   = (unsigned short*)take((size_t)n * FC * 2);
  unsigned short* h2   = (unsigned short*)take((size_t)n * FC * 2);
  unsigned short* wc1  = (unsigned short*)take(128 * 256 * 2);
  unsigned short* wc2  = (unsigned short*)take(128 * 256 * 2);
  unsigned short* wc3  = (unsigned short*)take(128 * 256 * 2);
  unsigned short* whb  = (unsigned short*)take(64 * 128 * 2);
  float* stats = (float*)take(3 * 256 * 4);   // 3 layers x (sum|sumsq)

  float invn = 1.0f / (float)n;

  // one-time conversions
  f2bf_kernel<<<(n * 16 + 255) / 256, 256, 0, stream>>>(x, x_bf, n * 16);
  pack_w_kernel<<<16, 256, 0, stream>>>(w1l, w1r, wc1);
  pack_w_kernel<<<16, 256, 0, stream>>>(w2l, w2r, wc2);
  pack_w_kernel<<<16, 256, 0, stream>>>(w3l, w3r, wc3);
  f2bf_kernel<<<4, 256, 0, stream>>>(wh, whb, 64 * 128 / 8);

  // CSR build
  hipMemsetAsync(deg, 0, (size_t)n * 4, stream);
  hipMemsetAsync(stats, 0, 3 * 256 * 4, stream);
  count_kernel<<<(e + 255) / 256, 256, 0, stream>>>(dstI, deg, rank, e);
  scan1_kernel<<<nb, 256, 0, stream>>>(deg, bsum, n);
  scan2_kernel<<<1, 256, 0, stream>>>(bsum, off, n, nb);
  scan3_kernel<<<nb, 256, 0, stream>>>(deg, bsum, off, n);
  fill_kernel<<<(e + 255) / 256, 256, 0, stream>>>(srcI, dstI, rank, off, csr, e);

  auto layer = [&](const unsigned short* in, unsigned short* out, const unsigned short* wc,
                   const float* bc, const float* g, const float* be, float* st) {
    aggregate_kernel<<<(n + 7) / 8, 256, 0, stream>>>(in, off, csr, agg, n);
    gemm_kernel<128, 256, true, true, true><<<(n + 63) / 64, 256, 0, stream>>>(
        agg, in, wc, bc, out, st, n);
    bn_apply_kernel<<<(n * 16 + 255) / 256, 256, 0, stream>>>(out, st, g, be, invn, n);
  };

  layer(x_bf, h1, wc1, b1c, g1, be1, stats);
  layer(h1,   h2, wc2, b2c, g2, be2, stats + 256);
  layer(h2,   h1, wc3, b3c, g3, be3, stats + 512);

  gemm_kernel<64, 128, false, false, false><<<(n + 63) / 64, 256, 0, stream>>>(
      h1, nullptr, whb, bh, d_out, nullptr, n);
}

// Round 6
// 289.362 us; speedup vs baseline: 2.6361x; 1.2115x over previous
//
#include <hip/hip_runtime.h>

static constexpr int FC = 128;

typedef __attribute__((ext_vector_type(8))) __bf16 bf16x8;
typedef __attribute__((ext_vector_type(4))) float f32x4;

__device__ __forceinline__ unsigned short f2bf(float f) {
  unsigned u = __float_as_uint(f);
  unsigned r = (u + 0x7FFF + ((u >> 16) & 1)) >> 16;
  return (unsigned short)r;
}
__device__ __forceinline__ float bf2f(unsigned short h) {
  return __uint_as_float((unsigned)h << 16);
}

// ---------------- fp32 -> bf16 conversion (8 elems/thread) ----------------
__global__ __launch_bounds__(256) void f2bf_kernel(const float* __restrict__ in,
                                                   unsigned short* __restrict__ out, int n8) {
  int i = blockIdx.x * 256 + threadIdx.x;
  if (i >= n8) return;
  const float* p = in + (size_t)i * 8;
  float4 a = *reinterpret_cast<const float4*>(p);
  float4 b = *reinterpret_cast<const float4*>(p + 4);
  ushort4 o0 = {f2bf(a.x), f2bf(a.y), f2bf(a.z), f2bf(a.w)};
  ushort4 o1 = {f2bf(b.x), f2bf(b.y), f2bf(b.z), f2bf(b.w)};
  unsigned short* q = out + (size_t)i * 8;
  *reinterpret_cast<ushort4*>(q) = o0;
  *reinterpret_cast<ushort4*>(q + 4) = o1;
}

// pack wl[128][128] | wr[128][128] -> wcat[128][256] bf16
__global__ __launch_bounds__(256) void pack_w_kernel(const float* __restrict__ wl,
                                                     const float* __restrict__ wr,
                                                     unsigned short* __restrict__ out) {
  int i = blockIdx.x * 256 + threadIdx.x;
  int row = i >> 5;
  int k8 = (i & 31) * 8;
  const float* src = (k8 < 128) ? (wl + (size_t)row * 128 + k8)
                                : (wr + (size_t)row * 128 + (k8 - 128));
  float4 a = *reinterpret_cast<const float4*>(src);
  float4 b = *reinterpret_cast<const float4*>(src + 4);
  ushort4 o0 = {f2bf(a.x), f2bf(a.y), f2bf(a.z), f2bf(a.w)};
  ushort4 o1 = {f2bf(b.x), f2bf(b.y), f2bf(b.z), f2bf(b.w)};
  unsigned short* q = out + (size_t)row * 256 + k8;
  *reinterpret_cast<ushort4*>(q) = o0;
  *reinterpret_cast<ushort4*>(q + 4) = o1;
}

// ---------------- CSR build ----------------
__global__ void count_kernel(const int* __restrict__ dst, int* __restrict__ deg,
                             int* __restrict__ rank, int e) {
  int i = blockIdx.x * blockDim.x + threadIdx.x;
  if (i < e) rank[i] = atomicAdd(&deg[dst[i]], 1);
}

__global__ __launch_bounds__(256) void scan1_kernel(const int* __restrict__ deg,
                                                    int* __restrict__ bsum, int n) {
  int i = blockIdx.x * 256 + threadIdx.x;
  int v = (i < n) ? deg[i] : 0;
  __shared__ int ls[256];
  ls[threadIdx.x] = v;
  __syncthreads();
  for (int d = 128; d > 0; d >>= 1) {
    if (threadIdx.x < (unsigned)d) ls[threadIdx.x] += ls[threadIdx.x + d];
    __syncthreads();
  }
  if (threadIdx.x == 0) bsum[blockIdx.x] = ls[0];
}

__global__ __launch_bounds__(256) void scan2_kernel(int* __restrict__ bsum,
                                                    int* __restrict__ off, int n, int nb) {
  __shared__ int ls[256];
  int t = threadIdx.x;
  int v = (t < nb) ? bsum[t] : 0;
  ls[t] = v;
  __syncthreads();
  for (int d = 1; d < 256; d <<= 1) {
    int u = (t >= d) ? ls[t - d] : 0;
    __syncthreads();
    ls[t] += u;
    __syncthreads();
  }
  if (t < nb) bsum[t] = ls[t] - v;
  if (t == 255) off[n] = ls[255];
}

__global__ __launch_bounds__(256) void scan3_kernel(const int* __restrict__ deg,
                                                    const int* __restrict__ bsum,
                                                    int* __restrict__ off, int n) {
  int i = blockIdx.x * 256 + threadIdx.x;
  int t = threadIdx.x;
  int v = (i < n) ? deg[i] : 0;
  __shared__ int ls[256];
  ls[t] = v;
  __syncthreads();
  for (int d = 1; d < 256; d <<= 1) {
    int u = (t >= d) ? ls[t - d] : 0;
    __syncthreads();
    ls[t] += u;
    __syncthreads();
  }
  if (i < n) off[i] = bsum[blockIdx.x] + ls[t] - v;
}

__global__ void fill_kernel(const int* __restrict__ src, const int* __restrict__ dst,
                            const int* __restrict__ rank, const int* __restrict__ off,
                            int* __restrict__ csr, int e) {
  int i = blockIdx.x * blockDim.x + threadIdx.x;
  if (i < e) csr[off[dst[i]] + rank[i]] = src[i];
}

// ---------------- mean aggregation (bf16 in/out): half-wave per node ----------------
__global__ __launch_bounds__(256) void aggregate_kernel(const unsigned short* __restrict__ x,
                                                        const int* __restrict__ off,
                                                        const int* __restrict__ csr,
                                                        unsigned short* __restrict__ agg, int n) {
  int hw = (int)((blockIdx.x * blockDim.x + threadIdx.x) >> 5);
  int lane = threadIdx.x & 31;
  if (hw >= n) return;
  int s0 = off[hw], s1 = off[hw + 1];
  float a0 = 0.f, a1 = 0.f, a2 = 0.f, a3 = 0.f;
  int j = s0;
  for (; j + 4 <= s1; j += 4) {
    int i0 = csr[j], i1 = csr[j + 1], i2 = csr[j + 2], i3 = csr[j + 3];
    ushort4 v0 = *reinterpret_cast<const ushort4*>(x + (size_t)i0 * FC + lane * 4);
    ushort4 v1 = *reinterpret_cast<const ushort4*>(x + (size_t)i1 * FC + lane * 4);
    ushort4 v2 = *reinterpret_cast<const ushort4*>(x + (size_t)i2 * FC + lane * 4);
    ushort4 v3 = *reinterpret_cast<const ushort4*>(x + (size_t)i3 * FC + lane * 4);
    a0 += (bf2f(v0.x) + bf2f(v1.x)) + (bf2f(v2.x) + bf2f(v3.x));
    a1 += (bf2f(v0.y) + bf2f(v1.y)) + (bf2f(v2.y) + bf2f(v3.y));
    a2 += (bf2f(v0.z) + bf2f(v1.z)) + (bf2f(v2.z) + bf2f(v3.z));
    a3 += (bf2f(v0.w) + bf2f(v1.w)) + (bf2f(v2.w) + bf2f(v3.w));
  }
  for (; j < s1; j++) {
    int i0 = csr[j];
    ushort4 v0 = *reinterpret_cast<const ushort4*>(x + (size_t)i0 * FC + lane * 4);
    a0 += bf2f(v0.x); a1 += bf2f(v0.y); a2 += bf2f(v0.z); a3 += bf2f(v0.w);
  }
  int d = s1 - s0;
  float inv = 1.0f / (float)(d > 0 ? d : 1);
  ushort4 o = {f2bf(a0 * inv), f2bf(a1 * inv), f2bf(a2 * inv), f2bf(a3 * inv)};
  *reinterpret_cast<ushort4*>(agg + (size_t)hw * FC + lane * 4) = o;
}

// ---------------- MFMA GEMM: W staged in LDS (XOR-swizzled), A preloaded ----------------
// C[nrows,NCOLS] = [A1|A2] @ W^T + bias. W: [NCOLS][KTOT] bf16 row-major.
// STATS: accumulate per-column sum/sumsq of C into stats[0..NCOLS) / stats[NCOLS..2N).
template <int NCOLS, int KTOT, bool DUAL, bool OUT_BF, bool STATS>
__global__ __launch_bounds__(256) void gemm_kernel(const unsigned short* __restrict__ A1,
                                                   const unsigned short* __restrict__ A2,
                                                   const unsigned short* __restrict__ W,
                                                   const float* __restrict__ bias,
                                                   void* __restrict__ Cout,
                                                   float* __restrict__ stats, int nrows) {
  constexpr int NKT = KTOT / 32;
  constexpr int NCF = NCOLS / 16;
  constexpr int RB = KTOT * 2;              // W row stride in bytes
  constexpr int WBYTES = NCOLS * KTOT * 2;  // 64 KB (layer) / 16 KB (head)
  __shared__ __align__(16) unsigned char Wl[WBYTES];

  int t = threadIdx.x;

  // stage W -> LDS with XOR swizzle (bank-conflict fix for stride-RB b128 reads)
  {
    constexpr int CH = WBYTES / 16 / 256;
#pragma unroll
    for (int c = 0; c < CH; c++) {
      int byte = (c * 256 + t) * 16;
      int row = byte / RB;
      int cb = byte % RB;
      float4 v = *reinterpret_cast<const float4*>(reinterpret_cast<const char*>(W) + byte);
      *reinterpret_cast<float4*>(Wl + row * RB + (cb ^ ((row & 7) << 4))) = v;
    }
  }

  int w = t >> 6;
  int l = t & 63;
  int lm = l & 15;
  int hi = l >> 4;
  int lk = hi * 8;
  int row = blockIdx.x * 64 + w * 16 + lm;
  int rclamp = min(row, nrows - 1);

  // preload ALL A fragments (independent global loads, one vmcnt drain)
  bf16x8 a[NKT];
#pragma unroll
  for (int kt = 0; kt < NKT; kt++) {
    const unsigned short* Ap;
    int kk;
    if (!DUAL || kt < NKT / 2) { Ap = A1; kk = kt * 32; }
    else                       { Ap = A2; kk = (kt - NKT / 2) * 32; }
    a[kt] = *reinterpret_cast<const bf16x8*>(Ap + (size_t)rclamp * 128 + kk + lk);
  }

  f32x4 acc[NCF];
#pragma unroll
  for (int cf = 0; cf < NCF; cf++) acc[cf] = {0.f, 0.f, 0.f, 0.f};

  __syncthreads();

#pragma unroll
  for (int kt = 0; kt < NKT; kt++) {
#pragma unroll
    for (int cf = 0; cf < NCF; cf++) {
      int r = cf * 16 + lm;
      int cb = kt * 64 + hi * 16;
      bf16x8 b = *reinterpret_cast<const bf16x8*>(Wl + r * RB + (cb ^ ((r & 7) << 4)));
      acc[cf] = __builtin_amdgcn_mfma_f32_16x16x32_bf16(a[kt], b, acc[cf], 0, 0, 0);
    }
  }

  __shared__ float wsum[4][NCOLS];
  __shared__ float wsq[4][NCOLS];

  int orow0 = blockIdx.x * 64 + w * 16 + hi * 4;
#pragma unroll
  for (int cf = 0; cf < NCF; cf++) {
    int col = cf * 16 + lm;
    float bs = bias[col];
    float s = 0.f, s2 = 0.f;
#pragma unroll
    for (int r = 0; r < 4; r++) {
      int orow = orow0 + r;
      bool ok = orow < nrows;
      float v = acc[cf][r] + bs;
      if (ok) {
        if (OUT_BF)
          ((unsigned short*)Cout)[(size_t)orow * NCOLS + col] = f2bf(v);
        else
          ((float*)Cout)[(size_t)orow * NCOLS + col] = v;
      }
      if (STATS) {
        float vv = ok ? v : 0.f;
        s += vv; s2 += vv * vv;
      }
    }
    if (STATS) {
      s  += __shfl_xor(s, 16);  s  += __shfl_xor(s, 32);
      s2 += __shfl_xor(s2, 16); s2 += __shfl_xor(s2, 32);
      if (l < 16) { wsum[w][col] = s; wsq[w][col] = s2; }
    }
  }
  if (STATS) {
    __syncthreads();
    if (t < NCOLS) {
      atomicAdd(&stats[t], wsum[0][t] + wsum[1][t] + wsum[2][t] + wsum[3][t]);
    } else if (t < 2 * NCOLS) {
      int c = t - NCOLS;
      atomicAdd(&stats[t], wsq[0][c] + wsq[1][c] + wsq[2][c] + wsq[3][c]);
    }
  }
}

// ---------------- BN finalize + apply + ReLU (folded) ----------------
__global__ __launch_bounds__(256) void bn_apply_kernel(unsigned short* __restrict__ h,
                                                       const float* __restrict__ stats,
                                                       const float* __restrict__ g,
                                                       const float* __restrict__ be,
                                                       float invn, int n) {
  __shared__ float sc[128], sh[128];
  int t = threadIdx.x;
  if (t < 128) {
    float mean = stats[t] * invn;
    float var = fmaxf(stats[128 + t] * invn - mean * mean, 0.f);
    float s = g[t] * rsqrtf(var + 1e-5f);
    sc[t] = s;
    sh[t] = be[t] - mean * s;
  }
  __syncthreads();
  int idx = blockIdx.x * 256 + t;
  if (idx >= n * 16) return;
  int c8 = (idx & 15) * 8;
  unsigned short* p = h + (size_t)idx * 8;
  ushort4 v0 = *reinterpret_cast<const ushort4*>(p);
  ushort4 v1 = *reinterpret_cast<const ushort4*>(p + 4);
  float o[8];
  o[0] = bf2f(v0.x); o[1] = bf2f(v0.y); o[2] = bf2f(v0.z); o[3] = bf2f(v0.w);
  o[4] = bf2f(v1.x); o[5] = bf2f(v1.y); o[6] = bf2f(v1.z); o[7] = bf2f(v1.w);
#pragma unroll
  for (int i = 0; i < 8; i++)
    o[i] = fmaxf(fmaf(o[i], sc[c8 + i], sh[c8 + i]), 0.f);
  ushort4 w0 = {f2bf(o[0]), f2bf(o[1]), f2bf(o[2]), f2bf(o[3])};
  ushort4 w1 = {f2bf(o[4]), f2bf(o[5]), f2bf(o[6]), f2bf(o[7])};
  *reinterpret_cast<ushort4*>(p) = w0;
  *reinterpret_cast<ushort4*>(p + 4) = w1;
}

// ---------------- launch ----------------
extern "C" void kernel_launch(void* const* d_in, const int* in_sizes, int n_in,
                              void* d_out, int out_size, void* d_ws, size_t ws_size,
                              hipStream_t stream) {
  const float* x   = (const float*)d_in[0];
  const int*   ei  = (const int*)d_in[1];
  const float* w1l = (const float*)d_in[2];
  const float* w1r = (const float*)d_in[3];
  const float* b1c = (const float*)d_in[4];
  const float* w2l = (const float*)d_in[5];
  const float* w2r = (const float*)d_in[6];
  const float* b2c = (const float*)d_in[7];
  const float* w3l = (const float*)d_in[8];
  const float* w3r = (const float*)d_in[9];
  const float* b3c = (const float*)d_in[10];
  const float* g1  = (const float*)d_in[11];
  const float* be1 = (const float*)d_in[12];
  const float* g2  = (const float*)d_in[13];
  const float* be2 = (const float*)d_in[14];
  const float* g3  = (const float*)d_in[15];
  const float* be3 = (const float*)d_in[16];
  const float* wh  = (const float*)d_in[17];
  const float* bh  = (const float*)d_in[18];

  int n = in_sizes[0] / FC;
  int e = in_sizes[1] / 2;
  const int* srcI = ei;
  const int* dstI = ei + e;

  char* p = (char*)d_ws;
  auto take = [&](size_t bytes) {
    char* q = p;
    p += (bytes + 255) & ~(size_t)255;
    return q;
  };
  int nb = (n + 255) / 256;
  int* deg  = (int*)take((size_t)n * 4);
  int* off  = (int*)take((size_t)(n + 1) * 4);
  int* bsum = (int*)take((size_t)nb * 4);
  int* rank = (int*)take((size_t)e * 4);
  int* csr  = (int*)take((size_t)e * 4);
  unsigned short* x_bf = (unsigned short*)take((size_t)n * FC * 2);
  unsigned short* agg  = (unsigned short*)take((size_t)n * FC * 2);
  unsigned short* h1   = (unsigned short*)take((size_t)n * FC * 2);
  unsigned short* h2   = (unsigned short*)take((size_t)n * FC * 2);
  unsigned short* wc1  = (unsigned short*)take(128 * 256 * 2);
  unsigned short* wc2  = (unsigned short*)take(128 * 256 * 2);
  unsigned short* wc3  = (unsigned short*)take(128 * 256 * 2);
  unsigned short* whb  = (unsigned short*)take(64 * 128 * 2);
  float* stats = (float*)take(3 * 256 * 4);   // 3 layers x (sum|sumsq)

  float invn = 1.0f / (float)n;

  // one-time conversions
  f2bf_kernel<<<(n * 16 + 255) / 256, 256, 0, stream>>>(x, x_bf, n * 16);
  pack_w_kernel<<<16, 256, 0, stream>>>(w1l, w1r, wc1);
  pack_w_kernel<<<16, 256, 0, stream>>>(w2l, w2r, wc2);
  pack_w_kernel<<<16, 256, 0, stream>>>(w3l, w3r, wc3);
  f2bf_kernel<<<4, 256, 0, stream>>>(wh, whb, 64 * 128 / 8);

  // CSR build
  hipMemsetAsync(deg, 0, (size_t)n * 4, stream);
  hipMemsetAsync(stats, 0, 3 * 256 * 4, stream);
  count_kernel<<<(e + 255) / 256, 256, 0, stream>>>(dstI, deg, rank, e);
  scan1_kernel<<<nb, 256, 0, stream>>>(deg, bsum, n);
  scan2_kernel<<<1, 256, 0, stream>>>(bsum, off, n, nb);
  scan3_kernel<<<nb, 256, 0, stream>>>(deg, bsum, off, n);
  fill_kernel<<<(e + 255) / 256, 256, 0, stream>>>(srcI, dstI, rank, off, csr, e);

  auto layer = [&](const unsigned short* in, unsigned short* out, const unsigned short* wc,
                   const float* bc, const float* g, const float* be, float* st) {
    aggregate_kernel<<<(n + 7) / 8, 256, 0, stream>>>(in, off, csr, agg, n);
    gemm_kernel<128, 256, true, true, true><<<(n + 63) / 64, 256, 0, stream>>>(
        agg, in, wc, bc, out, st, n);
    bn_apply_kernel<<<(n * 16 + 255) / 256, 256, 0, stream>>>(out, st, g, be, invn, n);
  };

  layer(x_bf, h1, wc1, b1c, g1, be1, stats);
  layer(h1,   h2, wc2, b2c, g2, be2, stats + 256);
  layer(h2,   h1, wc3, b3c, g3, be3, stats + 512);

  gemm_kernel<64, 128, false, false, false><<<(n + 63) / 64, 256, 0, stream>>>(
      h1, nullptr, whb, bh, d_out, nullptr, n);
}

// Round 8
// 276.287 us; speedup vs baseline: 2.7609x; 1.0473x over previous
//
#include <hip/hip_runtime.h>

static constexpr int FC = 128;

typedef __attribute__((ext_vector_type(8))) __bf16 bf16x8;
typedef __attribute__((ext_vector_type(4))) float f32x4;

__device__ __forceinline__ unsigned short f2bf(float f) {
  unsigned u = __float_as_uint(f);
  unsigned r = (u + 0x7FFF + ((u >> 16) & 1)) >> 16;
  return (unsigned short)r;
}
__device__ __forceinline__ float bf2f(unsigned short h) {
  return __uint_as_float((unsigned)h << 16);
}

// ---------------- zero deg + stats (replaces two slow in-graph memsets) ----------------
__global__ __launch_bounds__(256) void zero_kernel(int* __restrict__ deg,
                                                   float* __restrict__ stats, int n) {
  int i = blockIdx.x * 256 + threadIdx.x;
  if (i < n) deg[i] = 0;
  if (i < 768) stats[i] = 0.f;
}

// ---------------- fp32 -> bf16 conversion (8 elems/thread) ----------------
__global__ __launch_bounds__(256) void f2bf_kernel(const float* __restrict__ in,
                                                   unsigned short* __restrict__ out, int n8) {
  int i = blockIdx.x * 256 + threadIdx.x;
  if (i >= n8) return;
  const float* p = in + (size_t)i * 8;
  float4 a = *reinterpret_cast<const float4*>(p);
  float4 b = *reinterpret_cast<const float4*>(p + 4);
  ushort4 o0 = {f2bf(a.x), f2bf(a.y), f2bf(a.z), f2bf(a.w)};
  ushort4 o1 = {f2bf(b.x), f2bf(b.y), f2bf(b.z), f2bf(b.w)};
  unsigned short* q = out + (size_t)i * 8;
  *reinterpret_cast<ushort4*>(q) = o0;
  *reinterpret_cast<ushort4*>(q + 4) = o1;
}

// pack wl[128][128] | wr[128][128] -> wcat[128][256] bf16
__global__ __launch_bounds__(256) void pack_w_kernel(const float* __restrict__ wl,
                                                     const float* __restrict__ wr,
                                                     unsigned short* __restrict__ out) {
  int i = blockIdx.x * 256 + threadIdx.x;
  int row = i >> 5;
  int k8 = (i & 31) * 8;
  const float* src = (k8 < 128) ? (wl + (size_t)row * 128 + k8)
                                : (wr + (size_t)row * 128 + (k8 - 128));
  float4 a = *reinterpret_cast<const float4*>(src);
  float4 b = *reinterpret_cast<const float4*>(src + 4);
  ushort4 o0 = {f2bf(a.x), f2bf(a.y), f2bf(a.z), f2bf(a.w)};
  ushort4 o1 = {f2bf(b.x), f2bf(b.y), f2bf(b.z), f2bf(b.w)};
  unsigned short* q = out + (size_t)row * 256 + k8;
  *reinterpret_cast<ushort4*>(q) = o0;
  *reinterpret_cast<ushort4*>(q + 4) = o1;
}

// ---------------- CSR build ----------------
__global__ void count_kernel(const int* __restrict__ dst, int* __restrict__ deg,
                             int* __restrict__ rank, int e) {
  int i = blockIdx.x * blockDim.x + threadIdx.x;
  if (i < e) rank[i] = atomicAdd(&deg[dst[i]], 1);
}

__global__ __launch_bounds__(256) void scan1_kernel(const int* __restrict__ deg,
                                                    int* __restrict__ bsum, int n) {
  int i = blockIdx.x * 256 + threadIdx.x;
  int v = (i < n) ? deg[i] : 0;
  __shared__ int ls[256];
  ls[threadIdx.x] = v;
  __syncthreads();
  for (int d = 128; d > 0; d >>= 1) {
    if (threadIdx.x < (unsigned)d) ls[threadIdx.x] += ls[threadIdx.x + d];
    __syncthreads();
  }
  if (threadIdx.x == 0) bsum[blockIdx.x] = ls[0];
}

__global__ __launch_bounds__(256) void scan2_kernel(int* __restrict__ bsum,
                                                    int* __restrict__ off, int n, int nb) {
  __shared__ int ls[256];
  int t = threadIdx.x;
  int v = (t < nb) ? bsum[t] : 0;
  ls[t] = v;
  __syncthreads();
  for (int d = 1; d < 256; d <<= 1) {
    int u = (t >= d) ? ls[t - d] : 0;
    __syncthreads();
    ls[t] += u;
    __syncthreads();
  }
  if (t < nb) bsum[t] = ls[t] - v;
  if (t == 255) off[n] = ls[255];
}

__global__ __launch_bounds__(256) void scan3_kernel(const int* __restrict__ deg,
                                                    const int* __restrict__ bsum,
                                                    int* __restrict__ off, int n) {
  int i = blockIdx.x * 256 + threadIdx.x;
  int t = threadIdx.x;
  int v = (i < n) ? deg[i] : 0;
  __shared__ int ls[256];
  ls[t] = v;
  __syncthreads();
  for (int d = 1; d < 256; d <<= 1) {
    int u = (t >= d) ? ls[t - d] : 0;
    __syncthreads();
    ls[t] += u;
    __syncthreads();
  }
  if (i < n) off[i] = bsum[blockIdx.x] + ls[t] - v;
}

__global__ void fill_kernel(const int* __restrict__ src, const int* __restrict__ dst,
                            const int* __restrict__ rank, const int* __restrict__ off,
                            int* __restrict__ csr, int e) {
  int i = blockIdx.x * blockDim.x + threadIdx.x;
  if (i < e) csr[off[dst[i]] + rank[i]] = src[i];
}

// ---------------- mean aggregation, optional fused BN+ReLU on read ----------------
// BNIN: x holds PRE-BN values; apply relu(sc*v+sh) per gathered element, where
// sc/sh derive from stats (sum|sumsq), g, be of the PREVIOUS layer.
template <bool BNIN>
__global__ __launch_bounds__(256) void aggregate_kernel(const unsigned short* __restrict__ x,
                                                        const int* __restrict__ off,
                                                        const int* __restrict__ csr,
                                                        unsigned short* __restrict__ agg,
                                                        const float* __restrict__ stats,
                                                        const float* __restrict__ g,
                                                        const float* __restrict__ be,
                                                        float invn, int n) {
  int hw = (int)((blockIdx.x * blockDim.x + threadIdx.x) >> 5);
  int lane = threadIdx.x & 31;
  if (hw >= n) return;

  float sc0 = 1.f, sc1 = 1.f, sc2 = 1.f, sc3 = 1.f;
  float sh0 = 0.f, sh1 = 0.f, sh2 = 0.f, sh3 = 0.f;
  if (BNIN) {
    int c0 = lane * 4;
    float4 s  = *reinterpret_cast<const float4*>(stats + c0);
    float4 s2 = *reinterpret_cast<const float4*>(stats + 128 + c0);
    float4 gv = *reinterpret_cast<const float4*>(g + c0);
    float4 bv = *reinterpret_cast<const float4*>(be + c0);
    float m0 = s.x * invn, m1 = s.y * invn, m2 = s.z * invn, m3 = s.w * invn;
    sc0 = gv.x * rsqrtf(fmaxf(s2.x * invn - m0 * m0, 0.f) + 1e-5f);
    sc1 = gv.y * rsqrtf(fmaxf(s2.y * invn - m1 * m1, 0.f) + 1e-5f);
    sc2 = gv.z * rsqrtf(fmaxf(s2.z * invn - m2 * m2, 0.f) + 1e-5f);
    sc3 = gv.w * rsqrtf(fmaxf(s2.w * invn - m3 * m3, 0.f) + 1e-5f);
    sh0 = bv.x - m0 * sc0; sh1 = bv.y - m1 * sc1;
    sh2 = bv.z - m2 * sc2; sh3 = bv.w - m3 * sc3;
  }

  int s0 = off[hw], s1 = off[hw + 1];
  float a0 = 0.f, a1 = 0.f, a2 = 0.f, a3 = 0.f;

#define ACCV(v)                                                          \
  {                                                                      \
    float t0 = bf2f((v).x), t1 = bf2f((v).y), t2 = bf2f((v).z), t3 = bf2f((v).w); \
    if (BNIN) {                                                          \
      t0 = fmaxf(fmaf(t0, sc0, sh0), 0.f);                               \
      t1 = fmaxf(fmaf(t1, sc1, sh1), 0.f);                               \
      t2 = fmaxf(fmaf(t2, sc2, sh2), 0.f);                               \
      t3 = fmaxf(fmaf(t3, sc3, sh3), 0.f);                               \
    }                                                                    \
    a0 += t0; a1 += t1; a2 += t2; a3 += t3;                              \
  }

  int j = s0;
  for (; j + 4 <= s1; j += 4) {
    int i0 = csr[j], i1 = csr[j + 1], i2 = csr[j + 2], i3 = csr[j + 3];
    ushort4 v0 = *reinterpret_cast<const ushort4*>(x + (size_t)i0 * FC + lane * 4);
    ushort4 v1 = *reinterpret_cast<const ushort4*>(x + (size_t)i1 * FC + lane * 4);
    ushort4 v2 = *reinterpret_cast<const ushort4*>(x + (size_t)i2 * FC + lane * 4);
    ushort4 v3 = *reinterpret_cast<const ushort4*>(x + (size_t)i3 * FC + lane * 4);
    ACCV(v0) ACCV(v1) ACCV(v2) ACCV(v3)
  }
  for (; j < s1; j++) {
    int i0 = csr[j];
    ushort4 v0 = *reinterpret_cast<const ushort4*>(x + (size_t)i0 * FC + lane * 4);
    ACCV(v0)
  }
#undef ACCV

  int d = s1 - s0;
  float inv = 1.0f / (float)(d > 0 ? d : 1);
  ushort4 o = {f2bf(a0 * inv), f2bf(a1 * inv), f2bf(a2 * inv), f2bf(a3 * inv)};
  *reinterpret_cast<ushort4*>(agg + (size_t)hw * FC + lane * 4) = o;
}

// ---------------- MFMA GEMM: W in LDS (XOR-swizzled), A preloaded ----------------
// C[nrows,NCOLS] = [A1|A2] @ W^T + bias. W: [NCOLS][KTOT] bf16 row-major.
// STATS: accumulate per-column sum/sumsq of C into statsOut.
// BNIN: apply relu(sc*v+sh) (from statsIn/g/be) to the root-feature fragments
//       (A2 when DUAL, A1 when !DUAL) before the MFMAs.
template <int NCOLS, int KTOT, bool DUAL, bool OUT_BF, bool STATS, bool BNIN>
__global__ __launch_bounds__(256) void gemm_kernel(const unsigned short* __restrict__ A1,
                                                   const unsigned short* __restrict__ A2,
                                                   const unsigned short* __restrict__ W,
                                                   const float* __restrict__ bias,
                                                   void* __restrict__ Cout,
                                                   float* __restrict__ statsOut,
                                                   const float* __restrict__ statsIn,
                                                   const float* __restrict__ g,
                                                   const float* __restrict__ be,
                                                   float invn, int nrows) {
  constexpr int NKT = KTOT / 32;
  constexpr int NCF = NCOLS / 16;
  constexpr int RB = KTOT * 2;              // W row stride in bytes
  constexpr int WBYTES = NCOLS * KTOT * 2;  // 64 KB (layer) / 16 KB (head)
  __shared__ __align__(16) unsigned char Wl[WBYTES];
  __shared__ float scv[128], shv[128];

  int t = threadIdx.x;

  // stage W -> LDS with XOR swizzle
  {
    constexpr int CH = WBYTES / 16 / 256;
#pragma unroll
    for (int c = 0; c < CH; c++) {
      int byte = (c * 256 + t) * 16;
      int row = byte / RB;
      int cb = byte % RB;
      float4 v = *reinterpret_cast<const float4*>(reinterpret_cast<const char*>(W) + byte);
      *reinterpret_cast<float4*>(Wl + row * RB + (cb ^ ((row & 7) << 4))) = v;
    }
  }

  // BN scale/shift table for input channels
  if (BNIN && t < 128) {
    float mean = statsIn[t] * invn;
    float var = fmaxf(statsIn[128 + t] * invn - mean * mean, 0.f);
    float s = g[t] * rsqrtf(var + 1e-5f);
    scv[t] = s;
    shv[t] = be[t] - mean * s;
  }

  int w = t >> 6;
  int l = t & 63;
  int lm = l & 15;
  int hi = l >> 4;
  int lk = hi * 8;
  int row = blockIdx.x * 64 + w * 16 + lm;
  int rclamp = min(row, nrows - 1);

  // preload ALL A fragments
  bf16x8 a[NKT];
#pragma unroll
  for (int kt = 0; kt < NKT; kt++) {
    const unsigned short* Ap;
    int kk;
    if (!DUAL || kt < NKT / 2) { Ap = A1; kk = kt * 32; }
    else                       { Ap = A2; kk = (kt - NKT / 2) * 32; }
    a[kt] = *reinterpret_cast<const bf16x8*>(Ap + (size_t)rclamp * 128 + kk + lk);
  }

  f32x4 acc[NCF];
#pragma unroll
  for (int cf = 0; cf < NCF; cf++) acc[cf] = {0.f, 0.f, 0.f, 0.f};

  __syncthreads();

  // apply BN+ReLU to root-feature fragments (register-only, scv/shv from LDS)
  if (BNIN) {
#pragma unroll
    for (int kt = 0; kt < NKT; kt++) {
      if (!DUAL || kt >= NKT / 2) {
        int ch0 = (DUAL ? (kt - NKT / 2) : kt) * 32 + lk;
#pragma unroll
        for (int j = 0; j < 8; j++) {
          float v = (float)a[kt][j];
          v = fmaxf(fmaf(v, scv[ch0 + j], shv[ch0 + j]), 0.f);
          a[kt][j] = (__bf16)v;
        }
      }
    }
  }

#pragma unroll
  for (int kt = 0; kt < NKT; kt++) {
#pragma unroll
    for (int cf = 0; cf < NCF; cf++) {
      int r = cf * 16 + lm;
      int cb = kt * 64 + hi * 16;
      bf16x8 b = *reinterpret_cast<const bf16x8*>(Wl + r * RB + (cb ^ ((r & 7) << 4)));
      acc[cf] = __builtin_amdgcn_mfma_f32_16x16x32_bf16(a[kt], b, acc[cf], 0, 0, 0);
    }
  }

  __shared__ float wsum[4][NCOLS];
  __shared__ float wsq[4][NCOLS];

  int orow0 = blockIdx.x * 64 + w * 16 + hi * 4;
#pragma unroll
  for (int cf = 0; cf < NCF; cf++) {
    int col = cf * 16 + lm;
    float bs = bias[col];
    float s = 0.f, s2 = 0.f;
#pragma unroll
    for (int r = 0; r < 4; r++) {
      int orow = orow0 + r;
      bool ok = orow < nrows;
      float v = acc[cf][r] + bs;
      if (ok) {
        if (OUT_BF)
          ((unsigned short*)Cout)[(size_t)orow * NCOLS + col] = f2bf(v);
        else
          ((float*)Cout)[(size_t)orow * NCOLS + col] = v;
      }
      if (STATS) {
        float vv = ok ? v : 0.f;
        s += vv; s2 += vv * vv;
      }
    }
    if (STATS) {
      s  += __shfl_xor(s, 16);  s  += __shfl_xor(s, 32);
      s2 += __shfl_xor(s2, 16); s2 += __shfl_xor(s2, 32);
      if (l < 16) { wsum[w][col] = s; wsq[w][col] = s2; }
    }
  }
  if (STATS) {
    __syncthreads();
    if (t < NCOLS) {
      atomicAdd(&statsOut[t], wsum[0][t] + wsum[1][t] + wsum[2][t] + wsum[3][t]);
    } else if (t < 2 * NCOLS) {
      int c = t - NCOLS;
      atomicAdd(&statsOut[t], wsq[0][c] + wsq[1][c] + wsq[2][c] + wsq[3][c]);
    }
  }
}

// ---------------- launch ----------------
extern "C" void kernel_launch(void* const* d_in, const int* in_sizes, int n_in,
                              void* d_out, int out_size, void* d_ws, size_t ws_size,
                              hipStream_t stream) {
  const float* x   = (const float*)d_in[0];
  const int*   ei  = (const int*)d_in[1];
  const float* w1l = (const float*)d_in[2];
  const float* w1r = (const float*)d_in[3];
  const float* b1c = (const float*)d_in[4];
  const float* w2l = (const float*)d_in[5];
  const float* w2r = (const float*)d_in[6];
  const float* b2c = (const float*)d_in[7];
  const float* w3l = (const float*)d_in[8];
  const float* w3r = (const float*)d_in[9];
  const float* b3c = (const float*)d_in[10];
  const float* g1  = (const float*)d_in[11];
  const float* be1 = (const float*)d_in[12];
  const float* g2  = (const float*)d_in[13];
  const float* be2 = (const float*)d_in[14];
  const float* g3  = (const float*)d_in[15];
  const float* be3 = (const float*)d_in[16];
  const float* wh  = (const float*)d_in[17];
  const float* bh  = (const float*)d_in[18];

  int n = in_sizes[0] / FC;
  int e = in_sizes[1] / 2;
  const int* srcI = ei;
  const int* dstI = ei + e;

  char* p = (char*)d_ws;
  auto take = [&](size_t bytes) {
    char* q = p;
    p += (bytes + 255) & ~(size_t)255;
    return q;
  };
  int nb = (n + 255) / 256;
  int* deg  = (int*)take((size_t)n * 4);
  int* off  = (int*)take((size_t)(n + 1) * 4);
  int* bsum = (int*)take((size_t)nb * 4);
  int* rank = (int*)take((size_t)e * 4);
  int* csr  = (int*)take((size_t)e * 4);
  unsigned short* x_bf = (unsigned short*)take((size_t)n * FC * 2);
  unsigned short* agg  = (unsigned short*)take((size_t)n * FC * 2);
  unsigned short* h1   = (unsigned short*)take((size_t)n * FC * 2);
  unsigned short* h2   = (unsigned short*)take((size_t)n * FC * 2);
  unsigned short* wc1  = (unsigned short*)take(128 * 256 * 2);
  unsigned short* wc2  = (unsigned short*)take(128 * 256 * 2);
  unsigned short* wc3  = (unsigned short*)take(128 * 256 * 2);
  unsigned short* whb  = (unsigned short*)take(64 * 128 * 2);
  float* stats = (float*)take(3 * 256 * 4);   // 3 layers x (sum|sumsq)

  float invn = 1.0f / (float)n;

  // zero deg + all stats (one cheap kernel instead of two slow graph memsets)
  zero_kernel<<<nb, 256, 0, stream>>>(deg, stats, n);

  // one-time conversions
  f2bf_kernel<<<(n * 16 + 255) / 256, 256, 0, stream>>>(x, x_bf, n * 16);
  pack_w_kernel<<<16, 256, 0, stream>>>(w1l, w1r, wc1);
  pack_w_kernel<<<16, 256, 0, stream>>>(w2l, w2r, wc2);
  pack_w_kernel<<<16, 256, 0, stream>>>(w3l, w3r, wc3);
  f2bf_kernel<<<4, 256, 0, stream>>>(wh, whb, 64 * 128 / 8);

  // CSR build
  count_kernel<<<(e + 255) / 256, 256, 0, stream>>>(dstI, deg, rank, e);
  scan1_kernel<<<nb, 256, 0, stream>>>(deg, bsum, n);
  scan2_kernel<<<1, 256, 0, stream>>>(bsum, off, n, nb);
  scan3_kernel<<<nb, 256, 0, stream>>>(deg, bsum, off, n);
  fill_kernel<<<(e + 255) / 256, 256, 0, stream>>>(srcI, dstI, rank, off, csr, e);

  int gb = (n + 63) / 64;
  int ab = (n + 7) / 8;

  // layer 1: input x_bf (no BN on input)
  aggregate_kernel<false><<<ab, 256, 0, stream>>>(x_bf, off, csr, agg, nullptr, nullptr,
                                                  nullptr, invn, n);
  gemm_kernel<128, 256, true, true, true, false><<<gb, 256, 0, stream>>>(
      agg, x_bf, wc1, b1c, h1, stats, nullptr, nullptr, nullptr, invn, n);

  // layer 2: input h1 (pre-BN) with BN1 applied on read
  aggregate_kernel<true><<<ab, 256, 0, stream>>>(h1, off, csr, agg, stats, g1, be1, invn, n);
  gemm_kernel<128, 256, true, true, true, true><<<gb, 256, 0, stream>>>(
      agg, h1, wc2, b2c, h2, stats + 256, stats, g1, be1, invn, n);

  // layer 3: input h2 (pre-BN) with BN2 applied on read; output into h1 (free)
  aggregate_kernel<true><<<ab, 256, 0, stream>>>(h2, off, csr, agg, stats + 256, g2, be2, invn, n);
  gemm_kernel<128, 256, true, true, true, true><<<gb, 256, 0, stream>>>(
      agg, h2, wc3, b3c, h1, stats + 512, stats + 256, g2, be2, invn, n);

  // head: h1 = h3_pre with BN3 applied on read
  gemm_kernel<64, 128, false, false, false, true><<<gb, 256, 0, stream>>>(
      h1, nullptr, whb, bh, d_out, nullptr, stats + 512, g3, be3, invn, n);
}

// Round 9
// 275.580 us; speedup vs baseline: 2.7679x; 1.0026x over previous
//
#include <hip/hip_runtime.h>

static constexpr int FC = 128;

typedef __attribute__((ext_vector_type(8))) __bf16 bf16x8;
typedef __attribute__((ext_vector_type(4))) float f32x4;

__device__ __forceinline__ unsigned short f2bf(float f) {
  unsigned u = __float_as_uint(f);
  unsigned r = (u + 0x7FFF + ((u >> 16) & 1)) >> 16;
  return (unsigned short)r;
}
__device__ __forceinline__ float bf2f(unsigned short h) {
  return __uint_as_float((unsigned)h << 16);
}

// ---------------- zero deg + stats ----------------
__global__ __launch_bounds__(256) void zero_kernel(int* __restrict__ deg,
                                                   float* __restrict__ stats, int n) {
  int i = blockIdx.x * 256 + threadIdx.x;
  if (i < n) deg[i] = 0;
  if (i < 768) stats[i] = 0.f;
}

// ---------------- fused conversions: x->bf16, 3x packed W, head W ----------------
__global__ __launch_bounds__(256) void convert_kernel(
    const float* __restrict__ x, const float* __restrict__ w1l, const float* __restrict__ w1r,
    const float* __restrict__ w2l, const float* __restrict__ w2r,
    const float* __restrict__ w3l, const float* __restrict__ w3r,
    const float* __restrict__ wh,
    unsigned short* __restrict__ x_bf, unsigned short* __restrict__ wc1,
    unsigned short* __restrict__ wc2, unsigned short* __restrict__ wc3,
    unsigned short* __restrict__ whb, int nx8, int nxb) {
  int b = blockIdx.x;
  int t = threadIdx.x;
  if (b < nxb) {
    int i = b * 256 + t;
    if (i >= nx8) return;
    const float* p = x + (size_t)i * 8;
    float4 a = *reinterpret_cast<const float4*>(p);
    float4 c = *reinterpret_cast<const float4*>(p + 4);
    ushort4 o0 = {f2bf(a.x), f2bf(a.y), f2bf(a.z), f2bf(a.w)};
    ushort4 o1 = {f2bf(c.x), f2bf(c.y), f2bf(c.z), f2bf(c.w)};
    unsigned short* q = x_bf + (size_t)i * 8;
    *reinterpret_cast<ushort4*>(q) = o0;
    *reinterpret_cast<ushort4*>(q + 4) = o1;
    return;
  }
  int r = b - nxb;
  if (r < 48) {
    int layer = r >> 4;
    const float* wl = layer == 0 ? w1l : (layer == 1 ? w2l : w3l);
    const float* wr = layer == 0 ? w1r : (layer == 1 ? w2r : w3r);
    unsigned short* out = layer == 0 ? wc1 : (layer == 1 ? wc2 : wc3);
    int i = (r & 15) * 256 + t;   // 0..4095
    int row = i >> 5;
    int k8 = (i & 31) * 8;
    const float* src = (k8 < 128) ? (wl + (size_t)row * 128 + k8)
                                  : (wr + (size_t)row * 128 + (k8 - 128));
    float4 a = *reinterpret_cast<const float4*>(src);
    float4 c = *reinterpret_cast<const float4*>(src + 4);
    ushort4 o0 = {f2bf(a.x), f2bf(a.y), f2bf(a.z), f2bf(a.w)};
    ushort4 o1 = {f2bf(c.x), f2bf(c.y), f2bf(c.z), f2bf(c.w)};
    unsigned short* q = out + (size_t)row * 256 + k8;
    *reinterpret_cast<ushort4*>(q) = o0;
    *reinterpret_cast<ushort4*>(q + 4) = o1;
  } else {
    int i = (r - 48) * 256 + t;   // 0..1023
    const float* p = wh + (size_t)i * 8;
    float4 a = *reinterpret_cast<const float4*>(p);
    float4 c = *reinterpret_cast<const float4*>(p + 4);
    ushort4 o0 = {f2bf(a.x), f2bf(a.y), f2bf(a.z), f2bf(a.w)};
    ushort4 o1 = {f2bf(c.x), f2bf(c.y), f2bf(c.z), f2bf(c.w)};
    unsigned short* q = whb + (size_t)i * 8;
    *reinterpret_cast<ushort4*>(q) = o0;
    *reinterpret_cast<ushort4*>(q + 4) = o1;
  }
}

// ---------------- CSR build ----------------
__global__ void count_kernel(const int* __restrict__ dst, int* __restrict__ deg,
                             int* __restrict__ rank, int e) {
  int i = blockIdx.x * blockDim.x + threadIdx.x;
  if (i < e) rank[i] = atomicAdd(&deg[dst[i]], 1);
}

__global__ __launch_bounds__(256) void scan1_kernel(const int* __restrict__ deg,
                                                    int* __restrict__ bsum, int n) {
  int i = blockIdx.x * 256 + threadIdx.x;
  int v = (i < n) ? deg[i] : 0;
  __shared__ int ls[256];
  ls[threadIdx.x] = v;
  __syncthreads();
  for (int d = 128; d > 0; d >>= 1) {
    if (threadIdx.x < (unsigned)d) ls[threadIdx.x] += ls[threadIdx.x + d];
    __syncthreads();
  }
  if (threadIdx.x == 0) bsum[blockIdx.x] = ls[0];
}

// fused scan2+scan3: every block redundantly scans bsum (nb<=256) in LDS
__global__ __launch_bounds__(256) void scan23_kernel(const int* __restrict__ deg,
                                                     const int* __restrict__ bsum,
                                                     int* __restrict__ off, int n, int nb) {
  __shared__ int bls[256];
  __shared__ int ls[256];
  int t = threadIdx.x;
  int bv = (t < nb) ? bsum[t] : 0;
  bls[t] = bv;
  __syncthreads();
  for (int d = 1; d < 256; d <<= 1) {
    int u = (t >= d) ? bls[t - d] : 0;
    __syncthreads();
    bls[t] += u;
    __syncthreads();
  }
  int i = blockIdx.x * 256 + t;
  int v = (i < n) ? deg[i] : 0;
  ls[t] = v;
  __syncthreads();
  for (int d = 1; d < 256; d <<= 1) {
    int u = (t >= d) ? ls[t - d] : 0;
    __syncthreads();
    ls[t] += u;
    __syncthreads();
  }
  int base = blockIdx.x ? bls[blockIdx.x - 1] : 0;
  if (i < n) off[i] = base + ls[t] - v;
  if (blockIdx.x == 0 && t == 0) off[n] = bls[nb - 1];
}

__global__ void fill_kernel(const int* __restrict__ src, const int* __restrict__ dst,
                            const int* __restrict__ rank, const int* __restrict__ off,
                            int* __restrict__ csr, int e) {
  int i = blockIdx.x * blockDim.x + threadIdx.x;
  if (i < e) csr[off[dst[i]] + rank[i]] = src[i];
}

// ---------------- mean aggregation, unroll-8, optional fused BN+ReLU on read ----------------
template <bool BNIN>
__global__ __launch_bounds__(256) void aggregate_kernel(const unsigned short* __restrict__ x,
                                                        const int* __restrict__ off,
                                                        const int* __restrict__ csr,
                                                        unsigned short* __restrict__ agg,
                                                        const float* __restrict__ stats,
                                                        const float* __restrict__ g,
                                                        const float* __restrict__ be,
                                                        float invn, int n) {
  int hw = (int)((blockIdx.x * blockDim.x + threadIdx.x) >> 5);
  int lane = threadIdx.x & 31;
  if (hw >= n) return;

  float sc0 = 1.f, sc1 = 1.f, sc2 = 1.f, sc3 = 1.f;
  float sh0 = 0.f, sh1 = 0.f, sh2 = 0.f, sh3 = 0.f;
  if (BNIN) {
    int c0 = lane * 4;
    float4 s  = *reinterpret_cast<const float4*>(stats + c0);
    float4 s2 = *reinterpret_cast<const float4*>(stats + 128 + c0);
    float4 gv = *reinterpret_cast<const float4*>(g + c0);
    float4 bv = *reinterpret_cast<const float4*>(be + c0);
    float m0 = s.x * invn, m1 = s.y * invn, m2 = s.z * invn, m3 = s.w * invn;
    sc0 = gv.x * rsqrtf(fmaxf(s2.x * invn - m0 * m0, 0.f) + 1e-5f);
    sc1 = gv.y * rsqrtf(fmaxf(s2.y * invn - m1 * m1, 0.f) + 1e-5f);
    sc2 = gv.z * rsqrtf(fmaxf(s2.z * invn - m2 * m2, 0.f) + 1e-5f);
    sc3 = gv.w * rsqrtf(fmaxf(s2.w * invn - m3 * m3, 0.f) + 1e-5f);
    sh0 = bv.x - m0 * sc0; sh1 = bv.y - m1 * sc1;
    sh2 = bv.z - m2 * sc2; sh3 = bv.w - m3 * sc3;
  }

  int s0 = off[hw], s1 = off[hw + 1];
  float a0 = 0.f, a1 = 0.f, a2 = 0.f, a3 = 0.f;

#define ACCV(v)                                                                   \
  {                                                                               \
    float t0 = bf2f((v).x), t1 = bf2f((v).y), t2 = bf2f((v).z), t3 = bf2f((v).w); \
    if (BNIN) {                                                                   \
      t0 = fmaxf(fmaf(t0, sc0, sh0), 0.f);                                        \
      t1 = fmaxf(fmaf(t1, sc1, sh1), 0.f);                                        \
      t2 = fmaxf(fmaf(t2, sc2, sh2), 0.f);                                        \
      t3 = fmaxf(fmaf(t3, sc3, sh3), 0.f);                                        \
    }                                                                             \
    a0 += t0; a1 += t1; a2 += t2; a3 += t3;                                       \
  }

  int j = s0;
  for (; j + 8 <= s1; j += 8) {
    int i0 = csr[j],     i1 = csr[j + 1], i2 = csr[j + 2], i3 = csr[j + 3];
    int i4 = csr[j + 4], i5 = csr[j + 5], i6 = csr[j + 6], i7 = csr[j + 7];
    ushort4 v0 = *reinterpret_cast<const ushort4*>(x + (size_t)i0 * FC + lane * 4);
    ushort4 v1 = *reinterpret_cast<const ushort4*>(x + (size_t)i1 * FC + lane * 4);
    ushort4 v2 = *reinterpret_cast<const ushort4*>(x + (size_t)i2 * FC + lane * 4);
    ushort4 v3 = *reinterpret_cast<const ushort4*>(x + (size_t)i3 * FC + lane * 4);
    ushort4 v4 = *reinterpret_cast<const ushort4*>(x + (size_t)i4 * FC + lane * 4);
    ushort4 v5 = *reinterpret_cast<const ushort4*>(x + (size_t)i5 * FC + lane * 4);
    ushort4 v6 = *reinterpret_cast<const ushort4*>(x + (size_t)i6 * FC + lane * 4);
    ushort4 v7 = *reinterpret_cast<const ushort4*>(x + (size_t)i7 * FC + lane * 4);
    ACCV(v0) ACCV(v1) ACCV(v2) ACCV(v3) ACCV(v4) ACCV(v5) ACCV(v6) ACCV(v7)
  }
  if (j + 4 <= s1) {
    int i0 = csr[j], i1 = csr[j + 1], i2 = csr[j + 2], i3 = csr[j + 3];
    ushort4 v0 = *reinterpret_cast<const ushort4*>(x + (size_t)i0 * FC + lane * 4);
    ushort4 v1 = *reinterpret_cast<const ushort4*>(x + (size_t)i1 * FC + lane * 4);
    ushort4 v2 = *reinterpret_cast<const ushort4*>(x + (size_t)i2 * FC + lane * 4);
    ushort4 v3 = *reinterpret_cast<const ushort4*>(x + (size_t)i3 * FC + lane * 4);
    ACCV(v0) ACCV(v1) ACCV(v2) ACCV(v3)
    j += 4;
  }
  for (; j < s1; j++) {
    int i0 = csr[j];
    ushort4 v0 = *reinterpret_cast<const ushort4*>(x + (size_t)i0 * FC + lane * 4);
    ACCV(v0)
  }
#undef ACCV

  int d = s1 - s0;
  float inv = 1.0f / (float)(d > 0 ? d : 1);
  ushort4 o = {f2bf(a0 * inv), f2bf(a1 * inv), f2bf(a2 * inv), f2bf(a3 * inv)};
  *reinterpret_cast<ushort4*>(agg + (size_t)hw * FC + lane * 4) = o;
}

// ---------------- MFMA GEMM: W in LDS (XOR-swizzled), A preloaded ----------------
template <int NCOLS, int KTOT, bool DUAL, bool OUT_BF, bool STATS, bool BNIN>
__global__ __launch_bounds__(256) void gemm_kernel(const unsigned short* __restrict__ A1,
                                                   const unsigned short* __restrict__ A2,
                                                   const unsigned short* __restrict__ W,
                                                   const float* __restrict__ bias,
                                                   void* __restrict__ Cout,
                                                   float* __restrict__ statsOut,
                                                   const float* __restrict__ statsIn,
                                                   const float* __restrict__ g,
                                                   const float* __restrict__ be,
                                                   float invn, int nrows) {
  constexpr int NKT = KTOT / 32;
  constexpr int NCF = NCOLS / 16;
  constexpr int RB = KTOT * 2;
  constexpr int WBYTES = NCOLS * KTOT * 2;
  __shared__ __align__(16) unsigned char Wl[WBYTES];
  __shared__ float scv[128], shv[128];

  int t = threadIdx.x;

  {
    constexpr int CH = WBYTES / 16 / 256;
#pragma unroll
    for (int c = 0; c < CH; c++) {
      int byte = (c * 256 + t) * 16;
      int row = byte / RB;
      int cb = byte % RB;
      float4 v = *reinterpret_cast<const float4*>(reinterpret_cast<const char*>(W) + byte);
      *reinterpret_cast<float4*>(Wl + row * RB + (cb ^ ((row & 7) << 4))) = v;
    }
  }

  if (BNIN && t < 128) {
    float mean = statsIn[t] * invn;
    float var = fmaxf(statsIn[128 + t] * invn - mean * mean, 0.f);
    float s = g[t] * rsqrtf(var + 1e-5f);
    scv[t] = s;
    shv[t] = be[t] - mean * s;
  }

  int w = t >> 6;
  int l = t & 63;
  int lm = l & 15;
  int hi = l >> 4;
  int lk = hi * 8;
  int row = blockIdx.x * 64 + w * 16 + lm;
  int rclamp = min(row, nrows - 1);

  bf16x8 a[NKT];
#pragma unroll
  for (int kt = 0; kt < NKT; kt++) {
    const unsigned short* Ap;
    int kk;
    if (!DUAL || kt < NKT / 2) { Ap = A1; kk = kt * 32; }
    else                       { Ap = A2; kk = (kt - NKT / 2) * 32; }
    a[kt] = *reinterpret_cast<const bf16x8*>(Ap + (size_t)rclamp * 128 + kk + lk);
  }

  f32x4 acc[NCF];
#pragma unroll
  for (int cf = 0; cf < NCF; cf++) acc[cf] = {0.f, 0.f, 0.f, 0.f};

  __syncthreads();

  if (BNIN) {
#pragma unroll
    for (int kt = 0; kt < NKT; kt++) {
      if (!DUAL || kt >= NKT / 2) {
        int ch0 = (DUAL ? (kt - NKT / 2) : kt) * 32 + lk;
#pragma unroll
        for (int j = 0; j < 8; j++) {
          float v = (float)a[kt][j];
          v = fmaxf(fmaf(v, scv[ch0 + j], shv[ch0 + j]), 0.f);
          a[kt][j] = (__bf16)v;
        }
      }
    }
  }

#pragma unroll
  for (int kt = 0; kt < NKT; kt++) {
#pragma unroll
    for (int cf = 0; cf < NCF; cf++) {
      int r = cf * 16 + lm;
      int cb = kt * 64 + hi * 16;
      bf16x8 b = *reinterpret_cast<const bf16x8*>(Wl + r * RB + (cb ^ ((r & 7) << 4)));
      acc[cf] = __builtin_amdgcn_mfma_f32_16x16x32_bf16(a[kt], b, acc[cf], 0, 0, 0);
    }
  }

  __shared__ float wsum[4][NCOLS];
  __shared__ float wsq[4][NCOLS];

  int orow0 = blockIdx.x * 64 + w * 16 + hi * 4;
#pragma unroll
  for (int cf = 0; cf < NCF; cf++) {
    int col = cf * 16 + lm;
    float bs = bias[col];
    float s = 0.f, s2 = 0.f;
#pragma unroll
    for (int r = 0; r < 4; r++) {
      int orow = orow0 + r;
      bool ok = orow < nrows;
      float v = acc[cf][r] + bs;
      if (ok) {
        if (OUT_BF)
          ((unsigned short*)Cout)[(size_t)orow * NCOLS + col] = f2bf(v);
        else
          ((float*)Cout)[(size_t)orow * NCOLS + col] = v;
      }
      if (STATS) {
        float vv = ok ? v : 0.f;
        s += vv; s2 += vv * vv;
      }
    }
    if (STATS) {
      s  += __shfl_xor(s, 16);  s  += __shfl_xor(s, 32);
      s2 += __shfl_xor(s2, 16); s2 += __shfl_xor(s2, 32);
      if (l < 16) { wsum[w][col] = s; wsq[w][col] = s2; }
    }
  }
  if (STATS) {
    __syncthreads();
    if (t < NCOLS) {
      atomicAdd(&statsOut[t], wsum[0][t] + wsum[1][t] + wsum[2][t] + wsum[3][t]);
    } else if (t < 2 * NCOLS) {
      int c = t - NCOLS;
      atomicAdd(&statsOut[t], wsq[0][c] + wsq[1][c] + wsq[2][c] + wsq[3][c]);
    }
  }
}

// ---------------- launch ----------------
extern "C" void kernel_launch(void* const* d_in, const int* in_sizes, int n_in,
                              void* d_out, int out_size, void* d_ws, size_t ws_size,
                              hipStream_t stream) {
  const float* x   = (const float*)d_in[0];
  const int*   ei  = (const int*)d_in[1];
  const float* w1l = (const float*)d_in[2];
  const float* w1r = (const float*)d_in[3];
  const float* b1c = (const float*)d_in[4];
  const float* w2l = (const float*)d_in[5];
  const float* w2r = (const float*)d_in[6];
  const float* b2c = (const float*)d_in[7];
  const float* w3l = (const float*)d_in[8];
  const float* w3r = (const float*)d_in[9];
  const float* b3c = (const float*)d_in[10];
  const float* g1  = (const float*)d_in[11];
  const float* be1 = (const float*)d_in[12];
  const float* g2  = (const float*)d_in[13];
  const float* be2 = (const float*)d_in[14];
  const float* g3  = (const float*)d_in[15];
  const float* be3 = (const float*)d_in[16];
  const float* wh  = (const float*)d_in[17];
  const float* bh  = (const float*)d_in[18];

  int n = in_sizes[0] / FC;
  int e = in_sizes[1] / 2;
  const int* srcI = ei;
  const int* dstI = ei + e;

  char* p = (char*)d_ws;
  auto take = [&](size_t bytes) {
    char* q = p;
    p += (bytes + 255) & ~(size_t)255;
    return q;
  };
  int nb = (n + 255) / 256;
  int* deg  = (int*)take((size_t)n * 4);
  int* off  = (int*)take((size_t)(n + 1) * 4);
  int* bsum = (int*)take((size_t)nb * 4);
  int* rank = (int*)take((size_t)e * 4);
  int* csr  = (int*)take((size_t)e * 4);
  unsigned short* x_bf = (unsigned short*)take((size_t)n * FC * 2);
  unsigned short* agg  = (unsigned short*)take((size_t)n * FC * 2);
  unsigned short* h1   = (unsigned short*)take((size_t)n * FC * 2);
  unsigned short* h2   = (unsigned short*)take((size_t)n * FC * 2);
  unsigned short* wc1  = (unsigned short*)take(128 * 256 * 2);
  unsigned short* wc2  = (unsigned short*)take(128 * 256 * 2);
  unsigned short* wc3  = (unsigned short*)take(128 * 256 * 2);
  unsigned short* whb  = (unsigned short*)take(64 * 128 * 2);
  float* stats = (float*)take(3 * 256 * 4);

  float invn = 1.0f / (float)n;
  int nx8 = n * 16;
  int nxb = (nx8 + 255) / 256;

  zero_kernel<<<nb, 256, 0, stream>>>(deg, stats, n);
  convert_kernel<<<nxb + 52, 256, 0, stream>>>(x, w1l, w1r, w2l, w2r, w3l, w3r, wh,
                                               x_bf, wc1, wc2, wc3, whb, nx8, nxb);

  count_kernel<<<(e + 255) / 256, 256, 0, stream>>>(dstI, deg, rank, e);
  scan1_kernel<<<nb, 256, 0, stream>>>(deg, bsum, n);
  scan23_kernel<<<nb, 256, 0, stream>>>(deg, bsum, off, n, nb);
  fill_kernel<<<(e + 255) / 256, 256, 0, stream>>>(srcI, dstI, rank, off, csr, e);

  int gb = (n + 63) / 64;
  int ab = (n + 7) / 8;

  // layer 1
  aggregate_kernel<false><<<ab, 256, 0, stream>>>(x_bf, off, csr, agg, nullptr, nullptr,
                                                  nullptr, invn, n);
  gemm_kernel<128, 256, true, true, true, false><<<gb, 256, 0, stream>>>(
      agg, x_bf, wc1, b1c, h1, stats, nullptr, nullptr, nullptr, invn, n);

  // layer 2
  aggregate_kernel<true><<<ab, 256, 0, stream>>>(h1, off, csr, agg, stats, g1, be1, invn, n);
  gemm_kernel<128, 256, true, true, true, true><<<gb, 256, 0, stream>>>(
      agg, h1, wc2, b2c, h2, stats + 256, stats, g1, be1, invn, n);

  // layer 3
  aggregate_kernel<true><<<ab, 256, 0, stream>>>(h2, off, csr, agg, stats + 256, g2, be2, invn, n);
  gemm_kernel<128, 256, true, true, true, true><<<gb, 256, 0, stream>>>(
      agg, h2, wc3, b3c, h1, stats + 512, stats + 256, g2, be2, invn, n);

  // head
  gemm_kernel<64, 128, false, false, false, true><<<gb, 256, 0, stream>>>(
      h1, nullptr, whb, bh, d_out, nullptr, stats + 512, g3, be3, invn, n);
}

// Round 12
// 261.658 us; speedup vs baseline: 2.9152x; 1.0532x over previous
//
#include <hip/hip_runtime.h>

static constexpr int FC = 128;

typedef __attribute__((ext_vector_type(8))) __bf16 bf16x8;
typedef __attribute__((ext_vector_type(4))) float f32x4;

__device__ __forceinline__ unsigned short f2bf(float f) {
  unsigned u = __float_as_uint(f);
  unsigned r = (u + 0x7FFF + ((u >> 16) & 1)) >> 16;
  return (unsigned short)r;
}
__device__ __forceinline__ float bf2f(unsigned short h) {
  return __uint_as_float((unsigned)h << 16);
}
// pack 4 ints (-127..127) into 4 bytes
__device__ __forceinline__ unsigned pk_i8x4(int q0, int q1, int q2, int q3) {
  return (unsigned)(q0 & 0xff) | ((unsigned)(q1 & 0xff) << 8) |
         ((unsigned)(q2 & 0xff) << 16) | ((unsigned)(q3 & 0xff) << 24);
}

// ---------------- zero deg + stats ----------------
__global__ __launch_bounds__(256) void zero_kernel(int* __restrict__ deg,
                                                   float* __restrict__ stats, int n) {
  int i = blockIdx.x * 256 + threadIdx.x;
  if (i < n) deg[i] = 0;
  if (i < 768) stats[i] = 0.f;
}

// ---------------- fused conversions ----------------
// blocks [0,nxq): x rows -> bf16 + int8(row-scale). 8 rows/block (half-wave/row).
// blocks [nxq,nxq+48): packed layer weights. blocks [nxq+48,nxq+52): head W.
__global__ __launch_bounds__(256) void convert_kernel(
    const float* __restrict__ x, const float* __restrict__ w1l, const float* __restrict__ w1r,
    const float* __restrict__ w2l, const float* __restrict__ w2r,
    const float* __restrict__ w3l, const float* __restrict__ w3r,
    const float* __restrict__ wh,
    unsigned short* __restrict__ x_bf, unsigned* __restrict__ xi8,
    float* __restrict__ xsc,
    unsigned short* __restrict__ wc1,
    unsigned short* __restrict__ wc2, unsigned short* __restrict__ wc3,
    unsigned short* __restrict__ whb, int n, int nxq) {
  int b = blockIdx.x;
  int t = threadIdx.x;
  if (b < nxq) {
    int row = b * 8 + (t >> 5);
    int lane = t & 31;
    if (row >= n) return;
    float4 a = *reinterpret_cast<const float4*>(x + (size_t)row * FC + lane * 4);
    ushort4 o = {f2bf(a.x), f2bf(a.y), f2bf(a.z), f2bf(a.w)};
    *reinterpret_cast<ushort4*>(x_bf + (size_t)row * FC + lane * 4) = o;
    float m = fmaxf(fmaxf(fabsf(a.x), fabsf(a.y)), fmaxf(fabsf(a.z), fabsf(a.w)));
    m = fmaxf(m, __shfl_xor(m, 1));
    m = fmaxf(m, __shfl_xor(m, 2));
    m = fmaxf(m, __shfl_xor(m, 4));
    m = fmaxf(m, __shfl_xor(m, 8));
    m = fmaxf(m, __shfl_xor(m, 16));
    float inv = 127.0f / fmaxf(m, 1e-30f);
    int q0 = (int)rintf(a.x * inv), q1 = (int)rintf(a.y * inv);
    int q2 = (int)rintf(a.z * inv), q3 = (int)rintf(a.w * inv);
    xi8[(size_t)row * 32 + lane] = pk_i8x4(q0, q1, q2, q3);
    if (lane == 0) xsc[row] = m * (1.0f / 127.0f);
    return;
  }
  int r = b - nxq;
  if (r < 48) {
    int layer = r >> 4;
    const float* wl = layer == 0 ? w1l : (layer == 1 ? w2l : w3l);
    const float* wr = layer == 0 ? w1r : (layer == 1 ? w2r : w3r);
    unsigned short* out = layer == 0 ? wc1 : (layer == 1 ? wc2 : wc3);
    int i = (r & 15) * 256 + t;   // 0..4095
    int row = i >> 5;
    int k8 = (i & 31) * 8;
    const float* src = (k8 < 128) ? (wl + (size_t)row * 128 + k8)
                                  : (wr + (size_t)row * 128 + (k8 - 128));
    float4 a = *reinterpret_cast<const float4*>(src);
    float4 c = *reinterpret_cast<const float4*>(src + 4);
    ushort4 o0 = {f2bf(a.x), f2bf(a.y), f2bf(a.z), f2bf(a.w)};
    ushort4 o1 = {f2bf(c.x), f2bf(c.y), f2bf(c.z), f2bf(c.w)};
    unsigned short* q = out + (size_t)row * 256 + k8;
    *reinterpret_cast<ushort4*>(q) = o0;
    *reinterpret_cast<ushort4*>(q + 4) = o1;
  } else {
    int i = (r - 48) * 256 + t;   // 0..1023
    const float* p = wh + (size_t)i * 8;
    float4 a = *reinterpret_cast<const float4*>(p);
    float4 c = *reinterpret_cast<const float4*>(p + 4);
    ushort4 o0 = {f2bf(a.x), f2bf(a.y), f2bf(a.z), f2bf(a.w)};
    ushort4 o1 = {f2bf(c.x), f2bf(c.y), f2bf(c.z), f2bf(c.w)};
    unsigned short* q = whb + (size_t)i * 8;
    *reinterpret_cast<ushort4*>(q) = o0;
    *reinterpret_cast<ushort4*>(q + 4) = o1;
  }
}

// ---------------- CSR build ----------------
__global__ void count_kernel(const int* __restrict__ dst, int* __restrict__ deg,
                             int* __restrict__ rank, int e) {
  int i = blockIdx.x * blockDim.x + threadIdx.x;
  if (i < e) rank[i] = atomicAdd(&deg[dst[i]], 1);
}

__global__ __launch_bounds__(256) void scan1_kernel(const int* __restrict__ deg,
                                                    int* __restrict__ bsum, int n) {
  int i = blockIdx.x * 256 + threadIdx.x;
  int v = (i < n) ? deg[i] : 0;
  __shared__ int ls[256];
  ls[threadIdx.x] = v;
  __syncthreads();
  for (int d = 128; d > 0; d >>= 1) {
    if (threadIdx.x < (unsigned)d) ls[threadIdx.x] += ls[threadIdx.x + d];
    __syncthreads();
  }
  if (threadIdx.x == 0) bsum[blockIdx.x] = ls[0];
}

__global__ __launch_bounds__(256) void scan23_kernel(const int* __restrict__ deg,
                                                     const int* __restrict__ bsum,
                                                     int* __restrict__ off, int n, int nb) {
  __shared__ int bls[256];
  __shared__ int ls[256];
  int t = threadIdx.x;
  int bv = (t < nb) ? bsum[t] : 0;
  bls[t] = bv;
  __syncthreads();
  for (int d = 1; d < 256; d <<= 1) {
    int u = (t >= d) ? bls[t - d] : 0;
    __syncthreads();
    bls[t] += u;
    __syncthreads();
  }
  int i = blockIdx.x * 256 + t;
  int v = (i < n) ? deg[i] : 0;
  ls[t] = v;
  __syncthreads();
  for (int d = 1; d < 256; d <<= 1) {
    int u = (t >= d) ? ls[t - d] : 0;
    __syncthreads();
    ls[t] += u;
    __syncthreads();
  }
  int base = blockIdx.x ? bls[blockIdx.x - 1] : 0;
  if (i < n) off[i] = base + ls[t] - v;
  if (blockIdx.x == 0 && t == 0) off[n] = bls[nb - 1];
}

__global__ void fill_kernel(const int* __restrict__ src, const int* __restrict__ dst,
                            const int* __restrict__ rank, const int* __restrict__ off,
                            int* __restrict__ csr, int e) {
  int i = blockIdx.x * blockDim.x + threadIdx.x;
  if (i < e) csr[off[dst[i]] + rank[i]] = src[i];
}

// ---------------- mean aggregation over int8 rows (+4B scale), fused BN+ReLU on read ----------------
// xi8: [n][32] uints. xsc: [n] row scales. agg out: bf16 [n][128].
template <bool BNIN>
__global__ __launch_bounds__(256) void aggregate_kernel(const unsigned* __restrict__ xi8,
                                                        const float* __restrict__ xsc,
                                                        const int* __restrict__ off,
                                                        const int* __restrict__ csr,
                                                        unsigned short* __restrict__ agg,
                                                        const float* __restrict__ stats,
                                                        const float* __restrict__ g,
                                                        const float* __restrict__ be,
                                                        float invn, int n) {
  int hw = (int)((blockIdx.x * blockDim.x + threadIdx.x) >> 5);
  int lane = threadIdx.x & 31;
  if (hw >= n) return;

  float sc0 = 1.f, sc1 = 1.f, sc2 = 1.f, sc3 = 1.f;
  float sh0 = 0.f, sh1 = 0.f, sh2 = 0.f, sh3 = 0.f;
  if (BNIN) {
    int c0 = lane * 4;
    float4 s  = *reinterpret_cast<const float4*>(stats + c0);
    float4 s2 = *reinterpret_cast<const float4*>(stats + 128 + c0);
    float4 gv = *reinterpret_cast<const float4*>(g + c0);
    float4 bv = *reinterpret_cast<const float4*>(be + c0);
    float m0 = s.x * invn, m1 = s.y * invn, m2 = s.z * invn, m3 = s.w * invn;
    sc0 = gv.x * rsqrtf(fmaxf(s2.x * invn - m0 * m0, 0.f) + 1e-5f);
    sc1 = gv.y * rsqrtf(fmaxf(s2.y * invn - m1 * m1, 0.f) + 1e-5f);
    sc2 = gv.z * rsqrtf(fmaxf(s2.z * invn - m2 * m2, 0.f) + 1e-5f);
    sc3 = gv.w * rsqrtf(fmaxf(s2.w * invn - m3 * m3, 0.f) + 1e-5f);
    sh0 = bv.x - m0 * sc0; sh1 = bv.y - m1 * sc1;
    sh2 = bv.z - m2 * sc2; sh3 = bv.w - m3 * sc3;
  }

  int s0 = off[hw], s1 = off[hw + 1];
  float a0 = 0.f, a1 = 0.f, a2 = 0.f, a3 = 0.f;

#define ACCV(u, sv)                                               \
  {                                                               \
    float q0 = (float)(((int)(u) << 24) >> 24);                   \
    float q1 = (float)(((int)(u) << 16) >> 24);                   \
    float q2 = (float)(((int)(u) << 8) >> 24);                    \
    float q3 = (float)((int)(u) >> 24);                           \
    if (BNIN) {                                                   \
      a0 += fmaxf(fmaf(q0, (sv) * sc0, sh0), 0.f);                \
      a1 += fmaxf(fmaf(q1, (sv) * sc1, sh1), 0.f);                \
      a2 += fmaxf(fmaf(q2, (sv) * sc2, sh2), 0.f);                \
      a3 += fmaxf(fmaf(q3, (sv) * sc3, sh3), 0.f);                \
    } else {                                                      \
      a0 = fmaf(q0, (sv), a0);                                    \
      a1 = fmaf(q1, (sv), a1);                                    \
      a2 = fmaf(q2, (sv), a2);                                    \
      a3 = fmaf(q3, (sv), a3);                                    \
    }                                                             \
  }

  int j = s0;
  for (; j + 8 <= s1; j += 8) {
    int i0 = csr[j],     i1 = csr[j + 1], i2 = csr[j + 2], i3 = csr[j + 3];
    int i4 = csr[j + 4], i5 = csr[j + 5], i6 = csr[j + 6], i7 = csr[j + 7];
    unsigned u0 = xi8[(size_t)i0 * 32 + lane];
    unsigned u1 = xi8[(size_t)i1 * 32 + lane];
    unsigned u2 = xi8[(size_t)i2 * 32 + lane];
    unsigned u3 = xi8[(size_t)i3 * 32 + lane];
    unsigned u4 = xi8[(size_t)i4 * 32 + lane];
    unsigned u5 = xi8[(size_t)i5 * 32 + lane];
    unsigned u6 = xi8[(size_t)i6 * 32 + lane];
    unsigned u7 = xi8[(size_t)i7 * 32 + lane];
    float sv0 = xsc[i0], sv1 = xsc[i1], sv2 = xsc[i2], sv3 = xsc[i3];
    float sv4 = xsc[i4], sv5 = xsc[i5], sv6 = xsc[i6], sv7 = xsc[i7];
    ACCV(u0, sv0) ACCV(u1, sv1) ACCV(u2, sv2) ACCV(u3, sv3)
    ACCV(u4, sv4) ACCV(u5, sv5) ACCV(u6, sv6) ACCV(u7, sv7)
  }
  for (; j < s1; j++) {
    int i0 = csr[j];
    unsigned u0 = xi8[(size_t)i0 * 32 + lane];
    float sv0 = xsc[i0];
    ACCV(u0, sv0)
  }
#undef ACCV

  int d = s1 - s0;
  float inv = 1.0f / (float)(d > 0 ? d : 1);
  ushort4 o = {f2bf(a0 * inv), f2bf(a1 * inv), f2bf(a2 * inv), f2bf(a3 * inv)};
  *reinterpret_cast<ushort4*>(agg + (size_t)hw * FC + lane * 4) = o;
}

// ---------------- MFMA GEMM: W in LDS (XOR-swizzled), A preloaded ----------------
// OUT_I8: additionally store int8(v) (pre-BN) + per-row scale for next layer's gather.
template <int NCOLS, int KTOT, bool DUAL, bool OUT_BF, bool STATS, bool BNIN, bool OUT_I8>
__global__ __launch_bounds__(256) void gemm_kernel(const unsigned short* __restrict__ A1,
                                                   const unsigned short* __restrict__ A2,
                                                   const unsigned short* __restrict__ W,
                                                   const float* __restrict__ bias,
                                                   void* __restrict__ Cout,
                                                   unsigned char* __restrict__ h8,
                                                   float* __restrict__ hsc,
                                                   float* __restrict__ statsOut,
                                                   const float* __restrict__ statsIn,
                                                   const float* __restrict__ g,
                                                   const float* __restrict__ be,
                                                   float invn, int nrows) {
  constexpr int NKT = KTOT / 32;
  constexpr int NCF = NCOLS / 16;
  constexpr int RB = KTOT * 2;
  constexpr int WBYTES = NCOLS * KTOT * 2;
  __shared__ __align__(16) unsigned char Wl[WBYTES];
  __shared__ float scv[128], shv[128];

  int t = threadIdx.x;

  {
    constexpr int CH = WBYTES / 16 / 256;
#pragma unroll
    for (int c = 0; c < CH; c++) {
      int byte = (c * 256 + t) * 16;
      int row = byte / RB;
      int cb = byte % RB;
      float4 v = *reinterpret_cast<const float4*>(reinterpret_cast<const char*>(W) + byte);
      *reinterpret_cast<float4*>(Wl + row * RB + (cb ^ ((row & 7) << 4))) = v;
    }
  }

  if (BNIN && t < 128) {
    float mean = statsIn[t] * invn;
    float var = fmaxf(statsIn[128 + t] * invn - mean * mean, 0.f);
    float s = g[t] * rsqrtf(var + 1e-5f);
    scv[t] = s;
    shv[t] = be[t] - mean * s;
  }

  int w = t >> 6;
  int l = t & 63;
  int lm = l & 15;
  int hi = l >> 4;
  int lk = hi * 8;
  int row = blockIdx.x * 64 + w * 16 + lm;
  int rclamp = min(row, nrows - 1);

  bf16x8 a[NKT];
#pragma unroll
  for (int kt = 0; kt < NKT; kt++) {
    const unsigned short* Ap;
    int kk;
    if (!DUAL || kt < NKT / 2) { Ap = A1; kk = kt * 32; }
    else                       { Ap = A2; kk = (kt - NKT / 2) * 32; }
    a[kt] = *reinterpret_cast<const bf16x8*>(Ap + (size_t)rclamp * 128 + kk + lk);
  }

  f32x4 acc[NCF];
#pragma unroll
  for (int cf = 0; cf < NCF; cf++) acc[cf] = {0.f, 0.f, 0.f, 0.f};

  __syncthreads();

  if (BNIN) {
#pragma unroll
    for (int kt = 0; kt < NKT; kt++) {
      if (!DUAL || kt >= NKT / 2) {
        int ch0 = (DUAL ? (kt - NKT / 2) : kt) * 32 + lk;
#pragma unroll
        for (int j = 0; j < 8; j++) {
          float v = (float)a[kt][j];
          v = fmaxf(fmaf(v, scv[ch0 + j], shv[ch0 + j]), 0.f);
          a[kt][j] = (__bf16)v;
        }
      }
    }
  }

#pragma unroll
  for (int kt = 0; kt < NKT; kt++) {
#pragma unroll
    for (int cf = 0; cf < NCF; cf++) {
      int r = cf * 16 + lm;
      int cb = kt * 64 + hi * 16;
      bf16x8 b = *reinterpret_cast<const bf16x8*>(Wl + r * RB + (cb ^ ((r & 7) << 4)));
      acc[cf] = __builtin_amdgcn_mfma_f32_16x16x32_bf16(a[kt], b, acc[cf], 0, 0, 0);
    }
  }

  // fold bias in-place
#pragma unroll
  for (int cf = 0; cf < NCF; cf++) {
    float bs = bias[cf * 16 + lm];
#pragma unroll
    for (int r = 0; r < 4; r++) acc[cf][r] += bs;
  }

  // per-output-row scale for int8 (max over 8 cf in-lane, then across 16 lanes)
  float qinv[4], qs[4];
  if (OUT_I8) {
#pragma unroll
    for (int r = 0; r < 4; r++) {
      float m = 0.f;
#pragma unroll
      for (int cf = 0; cf < NCF; cf++) m = fmaxf(m, fabsf(acc[cf][r]));
      m = fmaxf(m, __shfl_xor(m, 1));
      m = fmaxf(m, __shfl_xor(m, 2));
      m = fmaxf(m, __shfl_xor(m, 4));
      m = fmaxf(m, __shfl_xor(m, 8));
      qinv[r] = 127.0f / fmaxf(m, 1e-30f);
      qs[r] = m * (1.0f / 127.0f);
    }
  }

  __shared__ float wsum[4][NCOLS];
  __shared__ float wsq[4][NCOLS];

  int orow0 = blockIdx.x * 64 + w * 16 + hi * 4;
#pragma unroll
  for (int cf = 0; cf < NCF; cf++) {
    int col = cf * 16 + lm;
    float s = 0.f, s2 = 0.f;
#pragma unroll
    for (int r = 0; r < 4; r++) {
      int orow = orow0 + r;
      bool ok = orow < nrows;
      float v = acc[cf][r];
      if (ok) {
        if (OUT_BF)
          ((unsigned short*)Cout)[(size_t)orow * NCOLS + col] = f2bf(v);
        else
          ((float*)Cout)[(size_t)orow * NCOLS + col] = v;
        if (OUT_I8)
          h8[(size_t)orow * NCOLS + col] = (unsigned char)((int)rintf(v * qinv[r]) & 0xff);
      }
      if (STATS) {
        float vv = ok ? v : 0.f;
        s += vv; s2 += vv * vv;
      }
    }
    if (STATS) {
      s  += __shfl_xor(s, 16);  s  += __shfl_xor(s, 32);
      s2 += __shfl_xor(s2, 16); s2 += __shfl_xor(s2, 32);
      if (l < 16) { wsum[w][col] = s; wsq[w][col] = s2; }
    }
  }
  if (OUT_I8 && lm == 0) {
#pragma unroll
    for (int r = 0; r < 4; r++) {
      int orow = orow0 + r;
      if (orow < nrows) hsc[orow] = qs[r];
    }
  }
  if (STATS) {
    __syncthreads();
    if (t < NCOLS) {
      atomicAdd(&statsOut[t], wsum[0][t] + wsum[1][t] + wsum[2][t] + wsum[3][t]);
    } else if (t < 2 * NCOLS) {
      int c = t - NCOLS;
      atomicAdd(&statsOut[t], wsq[0][c] + wsq[1][c] + wsq[2][c] + wsq[3][c]);
    }
  }
}

// ---------------- launch ----------------
extern "C" void kernel_launch(void* const* d_in, const int* in_sizes, int n_in,
                              void* d_out, int out_size, void* d_ws, size_t ws_size,
                              hipStream_t stream) {
  const float* x   = (const float*)d_in[0];
  const int*   ei  = (const int*)d_in[1];
  const float* w1l = (const float*)d_in[2];
  const float* w1r = (const float*)d_in[3];
  const float* b1c = (const float*)d_in[4];
  const float* w2l = (const float*)d_in[5];
  const float* w2r = (const float*)d_in[6];
  const float* b2c = (const float*)d_in[7];
  const float* w3l = (const float*)d_in[8];
  const float* w3r = (const float*)d_in[9];
  const float* b3c = (const float*)d_in[10];
  const float* g1  = (const float*)d_in[11];
  const float* be1 = (const float*)d_in[12];
  const float* g2  = (const float*)d_in[13];
  const float* be2 = (const float*)d_in[14];
  const float* g3  = (const float*)d_in[15];
  const float* be3 = (const float*)d_in[16];
  const float* wh  = (const float*)d_in[17];
  const float* bh  = (const float*)d_in[18];

  int n = in_sizes[0] / FC;
  int e = in_sizes[1] / 2;
  const int* srcI = ei;
  const int* dstI = ei + e;

  char* p = (char*)d_ws;
  auto take = [&](size_t bytes) {
    char* q = p;
    p += (bytes + 255) & ~(size_t)255;
    return q;
  };
  int nb = (n + 255) / 256;
  int* deg  = (int*)take((size_t)n * 4);
  int* off  = (int*)take((size_t)(n + 1) * 4);
  int* bsum = (int*)take((size_t)nb * 4);
  int* rank = (int*)take((size_t)e * 4);
  int* csr  = (int*)take((size_t)e * 4);
  unsigned short* x_bf = (unsigned short*)take((size_t)n * FC * 2);
  unsigned short* agg  = (unsigned short*)take((size_t)n * FC * 2);
  unsigned short* h1   = (unsigned short*)take((size_t)n * FC * 2);
  unsigned short* h2   = (unsigned short*)take((size_t)n * FC * 2);
  unsigned char*  ai8  = (unsigned char*)take((size_t)n * FC);   // shared int8 gather buffer
  float*          asc  = (float*)take((size_t)n * 4);            // per-row scales
  unsigned short* wc1  = (unsigned short*)take(128 * 256 * 2);
  unsigned short* wc2  = (unsigned short*)take(128 * 256 * 2);
  unsigned short* wc3  = (unsigned short*)take(128 * 256 * 2);
  unsigned short* whb  = (unsigned short*)take(64 * 128 * 2);
  float* stats = (float*)take(3 * 256 * 4);

  float invn = 1.0f / (float)n;
  int nxq = (n + 7) / 8;

  zero_kernel<<<nb, 256, 0, stream>>>(deg, stats, n);
  convert_kernel<<<nxq + 52, 256, 0, stream>>>(x, w1l, w1r, w2l, w2r, w3l, w3r, wh,
                                               x_bf, (unsigned*)ai8, asc,
                                               wc1, wc2, wc3, whb, n, nxq);

  count_kernel<<<(e + 255) / 256, 256, 0, stream>>>(dstI, deg, rank, e);
  scan1_kernel<<<nb, 256, 0, stream>>>(deg, bsum, n);
  scan23_kernel<<<nb, 256, 0, stream>>>(deg, bsum, off, n, nb);
  fill_kernel<<<(e + 255) / 256, 256, 0, stream>>>(srcI, dstI, rank, off, csr, e);

  int gb = (n + 63) / 64;
  int ab = (n + 7) / 8;

  // layer 1: gather int8(x); root = bf16 x; emit h1 bf16 + int8 into ai8/asc
  aggregate_kernel<false><<<ab, 256, 0, stream>>>((const unsigned*)ai8, asc, off, csr, agg,
                                                  nullptr, nullptr, nullptr, invn, n);
  gemm_kernel<128, 256, true, true, true, false, true><<<gb, 256, 0, stream>>>(
      agg, x_bf, wc1, b1c, h1, ai8, asc, stats, nullptr, nullptr, nullptr, invn, n);

  // layer 2: gather int8(h1) with BN1 on read; root = bf16 h1 (BN1 in gemm)
  aggregate_kernel<true><<<ab, 256, 0, stream>>>((const unsigned*)ai8, asc, off, csr, agg,
                                                 stats, g1, be1, invn, n);
  gemm_kernel<128, 256, true, true, true, true, true><<<gb, 256, 0, stream>>>(
      agg, h1, wc2, b2c, h2, ai8, asc, stats + 256, stats, g1, be1, invn, n);

  // layer 3: gather int8(h2) with BN2 on read; no int8 out (head reads bf16)
  aggregate_kernel<true><<<ab, 256, 0, stream>>>((const unsigned*)ai8, asc, off, csr, agg,
                                                 stats + 256, g2, be2, invn, n);
  gemm_kernel<128, 256, true, true, true, true, false><<<gb, 256, 0, stream>>>(
      agg, h2, wc3, b3c, h1, nullptr, nullptr, stats + 512, stats + 256, g2, be2, invn, n);

  // head: BN3 on read of h1
  gemm_kernel<64, 128, false, false, false, true, false><<<gb, 256, 0, stream>>>(
      h1, nullptr, whb, bh, d_out, nullptr, nullptr, nullptr, stats + 512, g3, be3, invn, n);
}